// Round 1
// baseline (4379.153 us; speedup 1.0000x reference)
//
#include <hip/hip_runtime.h>

#define DIM 128
#define LSZ 100000
#define CSZ 210000
#define ESZ 630000

// ---------------------------------------------------------------------------
// GEMM: Y[M,128] = act( sum_i Xi[M,128] @ Wi[128,128] + bias )
// NIN inputs (K split of a concatenated update matmul). SWAP: row j of X1 is
// read from row j^1 (the literal pair-swap for l2l). RELU applies to output.
// Tile: 64 rows x 128 cols per block of 256 threads; thread computes 4 rows x
// (4 + 4) cols. W staged in LDS in 64-row halves; X tile staged once per input.
// ---------------------------------------------------------------------------
template<int NIN, bool RELU, bool SWAP>
__launch_bounds__(256)
__global__ void gemm128(const float* __restrict__ X1, const float* __restrict__ W1,
                        const float* __restrict__ X2, const float* __restrict__ W2,
                        const float* __restrict__ X3, const float* __restrict__ W3,
                        const float* __restrict__ bias,
                        float* __restrict__ Y, int M)
{
    __shared__ float Xs[64][132];   // +4 pad keeps float4 alignment (528B rows)
    __shared__ float Ws[64][128];

    const int tid = threadIdx.x;
    const int r0t = blockIdx.x * 64;
    const int cg  = tid & 15;       // 16 col groups
    const int rg  = tid >> 4;       // 16 row groups
    const int c0  = cg * 4;         // cols c0..c0+3 and c0+64..c0+67
    const int r0  = rg * 4;         // rows r0..r0+3 (within tile)

    float acc[4][8];
    #pragma unroll
    for (int i = 0; i < 4; ++i)
        #pragma unroll
        for (int j = 0; j < 8; ++j) acc[i][j] = 0.0f;

    #pragma unroll
    for (int in = 0; in < NIN; ++in) {
        const float* X = (in == 0) ? X1 : ((in == 1) ? X2 : X3);
        const float* W = (in == 0) ? W1 : ((in == 1) ? W2 : W3);

        __syncthreads();            // previous k-loop done before Xs overwrite
        // stage X tile [64][128]
        #pragma unroll
        for (int i = 0; i < 8; ++i) {
            int fl = i * 256 + tid;        // float4 index within tile
            int r  = fl >> 5;              // 32 float4 per row
            int c4 = (fl & 31) << 2;
            int gr = r0t + r;
            float4 v = make_float4(0.f, 0.f, 0.f, 0.f);
            if (gr < M) {
                int sr = (SWAP && in == 0) ? (gr ^ 1) : gr;
                v = *reinterpret_cast<const float4*>(X + (size_t)sr * DIM + c4);
            }
            *reinterpret_cast<float4*>(&Xs[r][c4]) = v;
        }

        #pragma unroll
        for (int kh = 0; kh < 2; ++kh) {
            __syncthreads();        // prior Ws reads done (also publishes Xs)
            #pragma unroll
            for (int i = 0; i < 8; ++i) {
                int fl = i * 256 + tid;
                int r  = fl >> 5;
                int c4 = (fl & 31) << 2;
                *reinterpret_cast<float4*>(&Ws[r][c4]) =
                    *reinterpret_cast<const float4*>(W + (size_t)(kh * 64 + r) * DIM + c4);
            }
            __syncthreads();

            #pragma unroll 2
            for (int k4 = 0; k4 < 64; k4 += 4) {
                float xf[4][4];
                #pragma unroll
                for (int i = 0; i < 4; ++i)
                    *reinterpret_cast<float4*>(&xf[i][0]) =
                        *reinterpret_cast<const float4*>(&Xs[r0 + i][kh * 64 + k4]);
                #pragma unroll
                for (int kk = 0; kk < 4; ++kk) {
                    float wv[8];
                    *reinterpret_cast<float4*>(&wv[0]) =
                        *reinterpret_cast<const float4*>(&Ws[k4 + kk][c0]);
                    *reinterpret_cast<float4*>(&wv[4]) =
                        *reinterpret_cast<const float4*>(&Ws[k4 + kk][c0 + 64]);
                    #pragma unroll
                    for (int i = 0; i < 4; ++i)
                        #pragma unroll
                        for (int j = 0; j < 8; ++j)
                            acc[i][j] = fmaf(xf[i][kk], wv[j], acc[i][j]);
                }
            }
        }
    }

    // epilogue
    float4 b0 = *reinterpret_cast<const float4*>(bias + c0);
    float4 b1 = *reinterpret_cast<const float4*>(bias + c0 + 64);
    #pragma unroll
    for (int i = 0; i < 4; ++i) {
        int gr = r0t + r0 + i;
        if (gr < M) {
            float4 o0 = make_float4(acc[i][0] + b0.x, acc[i][1] + b0.y,
                                    acc[i][2] + b0.z, acc[i][3] + b0.w);
            float4 o1 = make_float4(acc[i][4] + b1.x, acc[i][5] + b1.y,
                                    acc[i][6] + b1.z, acc[i][7] + b1.w);
            if (RELU) {
                o0.x = fmaxf(o0.x, 0.f); o0.y = fmaxf(o0.y, 0.f);
                o0.z = fmaxf(o0.z, 0.f); o0.w = fmaxf(o0.w, 0.f);
                o1.x = fmaxf(o1.x, 0.f); o1.y = fmaxf(o1.y, 0.f);
                o1.z = fmaxf(o1.z, 0.f); o1.w = fmaxf(o1.w, 0.f);
            }
            *reinterpret_cast<float4*>(Y + (size_t)gr * DIM + c0)      = o0;
            *reinterpret_cast<float4*>(Y + (size_t)gr * DIM + c0 + 64) = o1;
        }
    }
}

// ordered-uint encoding for float atomicMax
__device__ __forceinline__ unsigned fenc(float f) {
    unsigned u = __float_as_uint(f);
    return (u & 0x80000000u) ? ~u : (u | 0x80000000u);
}
__device__ __forceinline__ float fdec(unsigned e) {
    unsigned u = (e & 0x80000000u) ? (e & 0x7FFFFFFFu) : ~e;
    return __uint_as_float(u);
}

// ---------------------------------------------------------------------------
// One wave per edge: both attention scores (l2c and c2l), leaky-relu,
// store score, atomicMax into per-clause running max (both softmaxes use
// c_edge_index, faithful to the reference).
// ---------------------------------------------------------------------------
__launch_bounds__(256)
__global__ void edge_scores(const int* __restrict__ le_idx, const int* __restrict__ ce_idx,
                            const float* __restrict__ l_emb, const float* __restrict__ c_emb,
                            const float* __restrict__ A, const float* __restrict__ B,
                            const float* __restrict__ c_att, const float* __restrict__ l_att,
                            float* __restrict__ S1, float* __restrict__ S2,
                            unsigned* __restrict__ M1u, unsigned* __restrict__ M2u)
{
    int w = (int)((blockIdx.x * (size_t)blockDim.x + threadIdx.x) >> 6);
    if (w >= ESZ) return;
    int lane = threadIdx.x & 63;
    int le = le_idx[w], ce = ce_idx[w];
    int d = lane * 2;

    float2 cv = *reinterpret_cast<const float2*>(c_emb + (size_t)ce * DIM + d);
    float2 av = *reinterpret_cast<const float2*>(A     + (size_t)le * DIM + d);
    float2 lv = *reinterpret_cast<const float2*>(l_emb + (size_t)le * DIM + d);
    float2 bv = *reinterpret_cast<const float2*>(B     + (size_t)ce * DIM + d);

    float s1 = cv.x * c_att[d] + cv.y * c_att[d + 1]
             + av.x * c_att[DIM + d] + av.y * c_att[DIM + d + 1];
    float s2 = lv.x * l_att[d] + lv.y * l_att[d + 1]
             + bv.x * l_att[DIM + d] + bv.y * l_att[DIM + d + 1];

    #pragma unroll
    for (int m = 32; m >= 1; m >>= 1) {
        s1 += __shfl_xor(s1, m);
        s2 += __shfl_xor(s2, m);
    }
    if (lane == 0) {
        s1 = (s1 > 0.f) ? s1 : 0.2f * s1;
        s2 = (s2 > 0.f) ? s2 : 0.2f * s2;
        S1[w] = s1; S2[w] = s2;
        atomicMax(M1u + ce, fenc(s1));
        atomicMax(M2u + ce, fenc(s2));
    }
}

// thread per edge: ex = exp(s - max[seg]); accumulate denominator
__launch_bounds__(256)
__global__ void edge_expsum(const int* __restrict__ ce_idx,
                            float* __restrict__ S1, float* __restrict__ S2,
                            const unsigned* __restrict__ M1u, const unsigned* __restrict__ M2u,
                            float* __restrict__ D1, float* __restrict__ D2)
{
    int e = blockIdx.x * blockDim.x + threadIdx.x;
    if (e >= ESZ) return;
    int ce = ce_idx[e];
    float ex1 = __expf(S1[e] - fdec(M1u[ce]));
    float ex2 = __expf(S2[e] - fdec(M2u[ce]));
    S1[e] = ex1; S2[e] = ex2;
    atomicAdd(D1 + ce, ex1);
    atomicAdd(D2 + ce, ex2);
}

// one wave per edge: normalized weight, atomic scatter of weighted message rows
__launch_bounds__(256)
__global__ void edge_aggregate(const int* __restrict__ le_idx, const int* __restrict__ ce_idx,
                               const float* __restrict__ S1, const float* __restrict__ S2,
                               const float* __restrict__ D1, const float* __restrict__ D2,
                               const float* __restrict__ A, const float* __restrict__ B,
                               float* __restrict__ AGC, float* __restrict__ AGL)
{
    int w = (int)((blockIdx.x * (size_t)blockDim.x + threadIdx.x) >> 6);
    if (w >= ESZ) return;
    int lane = threadIdx.x & 63;
    int le = le_idx[w], ce = ce_idx[w];
    float w1 = S1[w] / (D1[ce] + 1e-16f);
    float w2 = S2[w] / (D2[ce] + 1e-16f);
    int d = lane * 2;

    float2 av = *reinterpret_cast<const float2*>(A + (size_t)le * DIM + d);
    float2 bv = *reinterpret_cast<const float2*>(B + (size_t)ce * DIM + d);

    atomicAdd(AGC + (size_t)ce * DIM + d,     w1 * av.x);
    atomicAdd(AGC + (size_t)ce * DIM + d + 1, w1 * av.y);
    atomicAdd(AGL + (size_t)le * DIM + d,     w2 * bv.x);
    atomicAdd(AGL + (size_t)le * DIM + d + 1, w2 * bv.y);
}

extern "C" void kernel_launch(void* const* d_in, const int* in_sizes, int n_in,
                              void* d_out, int out_size, void* d_ws, size_t ws_size,
                              hipStream_t stream)
{
    const int*   le      = (const int*)  d_in[2];
    const int*   ce      = (const int*)  d_in[3];
    const float* l_emb0  = (const float*)d_in[4];
    const float* c_emb0  = (const float*)d_in[5];
    const float* l2c_w1  = (const float*)d_in[6];
    const float* l2c_b1  = (const float*)d_in[7];
    const float* l2c_w2  = (const float*)d_in[8];
    const float* l2c_b2  = (const float*)d_in[9];
    const float* c2l_w1  = (const float*)d_in[10];
    const float* c2l_b1  = (const float*)d_in[11];
    const float* c2l_w2  = (const float*)d_in[12];
    const float* c2l_b2  = (const float*)d_in[13];
    const float* l2l_w1  = (const float*)d_in[14];
    const float* l2l_b1  = (const float*)d_in[15];
    const float* l2l_w2  = (const float*)d_in[16];
    const float* l2l_b2  = (const float*)d_in[17];
    const float* c_att   = (const float*)d_in[18];
    const float* c_upd_w = (const float*)d_in[19];
    const float* c_upd_b = (const float*)d_in[20];
    const float* l_att   = (const float*)d_in[21];
    const float* l_upd_w = (const float*)d_in[22];
    const float* l_upd_b = (const float*)d_in[23];

    float* out = (float*)d_out;
    float* outL[3] = { out,
                       out + (size_t)LSZ * DIM,
                       out + 2 * (size_t)LSZ * DIM };
    float* outC[3] = { out + 3 * (size_t)LSZ * DIM,
                       out + 3 * (size_t)LSZ * DIM + (size_t)CSZ * DIM,
                       out + 3 * (size_t)LSZ * DIM + 2 * (size_t)CSZ * DIM };

    float* ws  = (float*)d_ws;
    float* A   = ws;                          // L*128  (l_msg_feat, later l2l_msg)
    float* Bm  = A   + (size_t)LSZ * DIM;     // C*128  (c_msg_feat)
    float* AGC = Bm  + (size_t)CSZ * DIM;     // C*128  (l2c_aggr)
    float* AGL = AGC + (size_t)CSZ * DIM;     // L*128  (c2l_aggr)
    float* S1  = AGL + (size_t)LSZ * DIM;     // E
    float* S2  = S1  + ESZ;                   // E
    unsigned* M1u = (unsigned*)(S2 + ESZ);    // C
    unsigned* M2u = M1u + CSZ;                // C
    float* D1  = (float*)(M2u + CSZ);         // C
    float* D2  = D1 + CSZ;                    // C

    // output slot 0 = input embeddings
    hipMemcpyAsync(outL[0], l_emb0, (size_t)LSZ * DIM * sizeof(float),
                   hipMemcpyDeviceToDevice, stream);
    hipMemcpyAsync(outC[0], c_emb0, (size_t)CSZ * DIM * sizeof(float),
                   hipMemcpyDeviceToDevice, stream);

    const int GL = (LSZ + 63) / 64;
    const int GC = (CSZ + 63) / 64;
    const int GE_WAVE = ESZ / 4;              // 1 wave per edge, 4 waves/block
    const int GE_THR  = (ESZ + 255) / 256;

    for (int it = 0; it < 2; ++it) {
        const float* l_in = (it == 0) ? l_emb0 : outL[1];
        const float* c_in = (it == 0) ? c_emb0 : outC[1];
        float* l_out = outL[it + 1];
        float* c_out = outC[it + 1];

        hipMemsetAsync(M1u, 0, CSZ * sizeof(unsigned), stream);
        hipMemsetAsync(M2u, 0, CSZ * sizeof(unsigned), stream);
        hipMemsetAsync(D1,  0, CSZ * sizeof(float), stream);
        hipMemsetAsync(D2,  0, CSZ * sizeof(float), stream);
        hipMemsetAsync(AGC, 0, (size_t)CSZ * DIM * sizeof(float), stream);
        hipMemsetAsync(AGL, 0, (size_t)LSZ * DIM * sizeof(float), stream);

        // l_msg_feat = MLP2(l_in)  -> A
        gemm128<1, true,  false><<<GL, 256, 0, stream>>>(l_in, l2c_w1, nullptr, nullptr, nullptr, nullptr, l2c_b1, A, LSZ);
        gemm128<1, false, false><<<GL, 256, 0, stream>>>(A,    l2c_w2, nullptr, nullptr, nullptr, nullptr, l2c_b2, A, LSZ);
        // c_msg_feat = MLP2(c_in)  -> B
        gemm128<1, true,  false><<<GC, 256, 0, stream>>>(c_in, c2l_w1, nullptr, nullptr, nullptr, nullptr, c2l_b1, Bm, CSZ);
        gemm128<1, false, false><<<GC, 256, 0, stream>>>(Bm,   c2l_w2, nullptr, nullptr, nullptr, nullptr, c2l_b2, Bm, CSZ);

        edge_scores<<<GE_WAVE, 256, 0, stream>>>(le, ce, l_in, c_in, A, Bm, c_att, l_att, S1, S2, M1u, M2u);
        edge_expsum<<<GE_THR, 256, 0, stream>>>(ce, S1, S2, M1u, M2u, D1, D2);
        edge_aggregate<<<GE_WAVE, 256, 0, stream>>>(le, ce, S1, S2, D1, D2, A, Bm, AGC, AGL);

        // l2l_msg = MLP2(pair-swapped l_in) -> A (A free after aggregation)
        gemm128<1, true,  true ><<<GL, 256, 0, stream>>>(l_in, l2l_w1, nullptr, nullptr, nullptr, nullptr, l2l_b1, A, LSZ);
        gemm128<1, false, false><<<GL, 256, 0, stream>>>(A,    l2l_w2, nullptr, nullptr, nullptr, nullptr, l2l_b2, A, LSZ);

        // c_out = [c_in, AGC] @ c_upd_w + b
        gemm128<2, false, false><<<GC, 256, 0, stream>>>(c_in, c_upd_w, AGC, c_upd_w + DIM * DIM,
                                                         nullptr, nullptr, c_upd_b, c_out, CSZ);
        // l_out = [l_in, AGL, l2l_msg] @ l_upd_w + b
        gemm128<3, false, false><<<GL, 256, 0, stream>>>(l_in, l_upd_w, AGL, l_upd_w + DIM * DIM,
                                                         A, l_upd_w + 2 * DIM * DIM, l_upd_b, l_out, LSZ);
    }
}

// Round 2
// 2613.073 us; speedup vs baseline: 1.6759x; 1.6759x over previous
//
#include <hip/hip_runtime.h>

#define DIM 128
#define LSZ 100000
#define CSZ 210000
#define ESZ 630000

// ---------------------------------------------------------------------------
// GEMM: Y[M,128] = act( sum_i Xi[M,128] @ Wi[128,128] + bias )
// ---------------------------------------------------------------------------
template<int NIN, bool RELU, bool SWAP>
__launch_bounds__(256)
__global__ void gemm128(const float* __restrict__ X1, const float* __restrict__ W1,
                        const float* __restrict__ X2, const float* __restrict__ W2,
                        const float* __restrict__ X3, const float* __restrict__ W3,
                        const float* __restrict__ bias,
                        float* __restrict__ Y, int M)
{
    __shared__ float Xs[64][132];
    __shared__ float Ws[64][128];

    const int tid = threadIdx.x;
    const int r0t = blockIdx.x * 64;
    const int cg  = tid & 15;
    const int rg  = tid >> 4;
    const int c0  = cg * 4;
    const int r0  = rg * 4;

    float acc[4][8];
    #pragma unroll
    for (int i = 0; i < 4; ++i)
        #pragma unroll
        for (int j = 0; j < 8; ++j) acc[i][j] = 0.0f;

    #pragma unroll
    for (int in = 0; in < NIN; ++in) {
        const float* X = (in == 0) ? X1 : ((in == 1) ? X2 : X3);
        const float* W = (in == 0) ? W1 : ((in == 1) ? W2 : W3);

        __syncthreads();
        #pragma unroll
        for (int i = 0; i < 8; ++i) {
            int fl = i * 256 + tid;
            int r  = fl >> 5;
            int c4 = (fl & 31) << 2;
            int gr = r0t + r;
            float4 v = make_float4(0.f, 0.f, 0.f, 0.f);
            if (gr < M) {
                int sr = (SWAP && in == 0) ? (gr ^ 1) : gr;
                v = *reinterpret_cast<const float4*>(X + (size_t)sr * DIM + c4);
            }
            *reinterpret_cast<float4*>(&Xs[r][c4]) = v;
        }

        #pragma unroll
        for (int kh = 0; kh < 2; ++kh) {
            __syncthreads();
            #pragma unroll
            for (int i = 0; i < 8; ++i) {
                int fl = i * 256 + tid;
                int r  = fl >> 5;
                int c4 = (fl & 31) << 2;
                *reinterpret_cast<float4*>(&Ws[r][c4]) =
                    *reinterpret_cast<const float4*>(W + (size_t)(kh * 64 + r) * DIM + c4);
            }
            __syncthreads();

            #pragma unroll 2
            for (int k4 = 0; k4 < 64; k4 += 4) {
                float xf[4][4];
                #pragma unroll
                for (int i = 0; i < 4; ++i)
                    *reinterpret_cast<float4*>(&xf[i][0]) =
                        *reinterpret_cast<const float4*>(&Xs[r0 + i][kh * 64 + k4]);
                #pragma unroll
                for (int kk = 0; kk < 4; ++kk) {
                    float wv[8];
                    *reinterpret_cast<float4*>(&wv[0]) =
                        *reinterpret_cast<const float4*>(&Ws[k4 + kk][c0]);
                    *reinterpret_cast<float4*>(&wv[4]) =
                        *reinterpret_cast<const float4*>(&Ws[k4 + kk][c0 + 64]);
                    #pragma unroll
                    for (int i = 0; i < 4; ++i)
                        #pragma unroll
                        for (int j = 0; j < 8; ++j)
                            acc[i][j] = fmaf(xf[i][kk], wv[j], acc[i][j]);
                }
            }
        }
    }

    float4 b0 = *reinterpret_cast<const float4*>(bias + c0);
    float4 b1 = *reinterpret_cast<const float4*>(bias + c0 + 64);
    #pragma unroll
    for (int i = 0; i < 4; ++i) {
        int gr = r0t + r0 + i;
        if (gr < M) {
            float4 o0 = make_float4(acc[i][0] + b0.x, acc[i][1] + b0.y,
                                    acc[i][2] + b0.z, acc[i][3] + b0.w);
            float4 o1 = make_float4(acc[i][4] + b1.x, acc[i][5] + b1.y,
                                    acc[i][6] + b1.z, acc[i][7] + b1.w);
            if (RELU) {
                o0.x = fmaxf(o0.x, 0.f); o0.y = fmaxf(o0.y, 0.f);
                o0.z = fmaxf(o0.z, 0.f); o0.w = fmaxf(o0.w, 0.f);
                o1.x = fmaxf(o1.x, 0.f); o1.y = fmaxf(o1.y, 0.f);
                o1.z = fmaxf(o1.z, 0.f); o1.w = fmaxf(o1.w, 0.f);
            }
            *reinterpret_cast<float4*>(Y + (size_t)gr * DIM + c0)      = o0;
            *reinterpret_cast<float4*>(Y + (size_t)gr * DIM + c0 + 64) = o1;
        }
    }
}

// ---------------------------------------------------------------------------
// CSR build: histogram -> exclusive scan -> scatter
// ---------------------------------------------------------------------------
__launch_bounds__(256)
__global__ void hist_kernel(const int* __restrict__ le, const int* __restrict__ ce,
                            unsigned* __restrict__ cnt_c, unsigned* __restrict__ cnt_l)
{
    int e = blockIdx.x * blockDim.x + threadIdx.x;
    if (e >= ESZ) return;
    atomicAdd(cnt_c + ce[e], 1u);
    atomicAdd(cnt_l + le[e], 1u);
}

// 1024 elements per block of 256 threads (4/thread)
__launch_bounds__(256)
__global__ void scan_partial(const unsigned* __restrict__ in, unsigned* __restrict__ out,
                             unsigned* __restrict__ bsum, int n)
{
    __shared__ unsigned s[256];
    int tid  = threadIdx.x;
    int base = blockIdx.x * 1024 + tid * 4;
    unsigned v[4];
    #pragma unroll
    for (int k = 0; k < 4; ++k) v[k] = (base + k < n) ? in[base + k] : 0u;
    unsigned tsum = v[0] + v[1] + v[2] + v[3];
    s[tid] = tsum;
    __syncthreads();
    for (int off = 1; off < 256; off <<= 1) {
        unsigned t = (tid >= off) ? s[tid - off] : 0u;
        __syncthreads();
        s[tid] += t;
        __syncthreads();
    }
    unsigned excl = s[tid] - tsum;
    unsigned run = excl;
    #pragma unroll
    for (int k = 0; k < 4; ++k) {
        if (base + k < n) out[base + k] = run;
        run += v[k];
    }
    if (tid == 255) bsum[blockIdx.x] = s[255];
}

__launch_bounds__(256)
__global__ void scan_top(unsigned* __restrict__ bsum, int nb)
{
    __shared__ unsigned s[256];
    int tid = threadIdx.x;
    unsigned v = (tid < nb) ? bsum[tid] : 0u;
    s[tid] = v;
    __syncthreads();
    for (int off = 1; off < 256; off <<= 1) {
        unsigned t = (tid >= off) ? s[tid - off] : 0u;
        __syncthreads();
        s[tid] += t;
        __syncthreads();
    }
    if (tid < nb) bsum[tid] = s[tid] - v;
}

__launch_bounds__(256)
__global__ void scan_add(unsigned* __restrict__ out, const unsigned* __restrict__ bsum,
                         int n, unsigned total)
{
    int i = blockIdx.x * blockDim.x + threadIdx.x;
    if (i < n) out[i] += bsum[i >> 10];
    if (i == 0) out[n] = total;
}

__launch_bounds__(256)
__global__ void scatter_kernel(const int* __restrict__ le, const int* __restrict__ ce,
                               unsigned* __restrict__ cur_c, unsigned* __restrict__ cur_l,
                               unsigned* __restrict__ perm_c, unsigned* __restrict__ perm_l)
{
    int e = blockIdx.x * blockDim.x + threadIdx.x;
    if (e >= ESZ) return;
    unsigned p1 = atomicAdd(cur_c + ce[e], 1u);
    perm_c[p1] = (unsigned)e;
    unsigned p2 = atomicAdd(cur_l + le[e], 1u);
    perm_l[p2] = (unsigned)e;
}

// ---------------------------------------------------------------------------
// Per-node attention dot products (wave per node, 2 dots at once)
// clause c: pc1[c] = dot(c_att[0:128],   c_emb[c]);  qc2[c] = dot(l_att[128:256], B[c])
// literal l: ql1[l] = dot(c_att[128:256], A[l]);     pl2[l] = dot(l_att[0:128],   l_emb[l])
// ---------------------------------------------------------------------------
__launch_bounds__(256)
__global__ void gemv_c(const float* __restrict__ c_emb, const float* __restrict__ Bm,
                       const float* __restrict__ c_att, const float* __restrict__ l_att,
                       float* __restrict__ pc1, float* __restrict__ qc2)
{
    int w = (int)((blockIdx.x * (size_t)blockDim.x + threadIdx.x) >> 6);
    if (w >= CSZ) return;
    int lane = threadIdx.x & 63;
    int d = lane * 2;
    float2 cv = *reinterpret_cast<const float2*>(c_emb + (size_t)w * DIM + d);
    float2 bv = *reinterpret_cast<const float2*>(Bm    + (size_t)w * DIM + d);
    float2 a1 = *reinterpret_cast<const float2*>(c_att + d);
    float2 a2 = *reinterpret_cast<const float2*>(l_att + DIM + d);
    float s1 = cv.x * a1.x + cv.y * a1.y;
    float s2 = bv.x * a2.x + bv.y * a2.y;
    #pragma unroll
    for (int m = 32; m >= 1; m >>= 1) {
        s1 += __shfl_xor(s1, m);
        s2 += __shfl_xor(s2, m);
    }
    if (lane == 0) { pc1[w] = s1; qc2[w] = s2; }
}

__launch_bounds__(256)
__global__ void gemv_l(const float* __restrict__ l_emb, const float* __restrict__ A,
                       const float* __restrict__ c_att, const float* __restrict__ l_att,
                       float* __restrict__ ql1, float* __restrict__ pl2)
{
    int w = (int)((blockIdx.x * (size_t)blockDim.x + threadIdx.x) >> 6);
    if (w >= LSZ) return;
    int lane = threadIdx.x & 63;
    int d = lane * 2;
    float2 av = *reinterpret_cast<const float2*>(A     + (size_t)w * DIM + d);
    float2 lv = *reinterpret_cast<const float2*>(l_emb + (size_t)w * DIM + d);
    float2 a1 = *reinterpret_cast<const float2*>(c_att + DIM + d);
    float2 a2 = *reinterpret_cast<const float2*>(l_att + d);
    float s1 = av.x * a1.x + av.y * a1.y;
    float s2 = lv.x * a2.x + lv.y * a2.y;
    #pragma unroll
    for (int m = 32; m >= 1; m >>= 1) {
        s1 += __shfl_xor(s1, m);
        s2 += __shfl_xor(s2, m);
    }
    if (lane == 0) { ql1[w] = s1; pl2[w] = s2; }
}

// per-edge score assembly + leaky-relu
__launch_bounds__(256)
__global__ void edge_score(const int* __restrict__ le_idx, const int* __restrict__ ce_idx,
                           const float* __restrict__ pc1, const float* __restrict__ ql1,
                           const float* __restrict__ pl2, const float* __restrict__ qc2,
                           float* __restrict__ S1, float* __restrict__ S2)
{
    int e = blockIdx.x * blockDim.x + threadIdx.x;
    if (e >= ESZ) return;
    int le = le_idx[e], ce = ce_idx[e];
    float s1 = pc1[ce] + ql1[le];
    float s2 = pl2[le] + qc2[ce];
    s1 = (s1 > 0.f) ? s1 : 0.2f * s1;
    s2 = (s2 > 0.f) ? s2 : 0.2f * s2;
    S1[e] = s1;
    S2[e] = s2;
}

// thread per clause: exact segment max, exp in place, denominators
__launch_bounds__(256)
__global__ void seg_softmax(const unsigned* __restrict__ base_c, const unsigned* __restrict__ perm_c,
                            float* __restrict__ S1, float* __restrict__ S2,
                            float* __restrict__ D1, float* __restrict__ D2)
{
    int c = blockIdx.x * blockDim.x + threadIdx.x;
    if (c >= CSZ) return;
    unsigned b0 = base_c[c], b1 = base_c[c + 1];
    float m1 = -1e30f, m2 = -1e30f;
    for (unsigned j = b0; j < b1; ++j) {
        unsigned e = perm_c[j];
        m1 = fmaxf(m1, S1[e]);
        m2 = fmaxf(m2, S2[e]);
    }
    float d1 = 0.f, d2 = 0.f;
    for (unsigned j = b0; j < b1; ++j) {
        unsigned e = perm_c[j];
        float ex1 = __expf(S1[e] - m1);
        float ex2 = __expf(S2[e] - m2);
        S1[e] = ex1; S2[e] = ex2;
        d1 += ex1; d2 += ex2;
    }
    D1[c] = d1; D2[c] = d2;
}

// wave per clause: AGC[c] = sum_e w1[e] * A[le[e]]
__launch_bounds__(256)
__global__ void aggr_c(const unsigned* __restrict__ base_c, const unsigned* __restrict__ perm_c,
                       const int* __restrict__ le_idx,
                       const float* __restrict__ S1, const float* __restrict__ D1,
                       const float* __restrict__ A, float* __restrict__ AGC)
{
    int w = (int)((blockIdx.x * (size_t)blockDim.x + threadIdx.x) >> 6);
    if (w >= CSZ) return;
    int lane = threadIdx.x & 63;
    int d = lane * 2;
    unsigned b0 = base_c[w], b1 = base_c[w + 1];
    float invd = 1.f / (D1[w] + 1e-16f);
    float ax = 0.f, ay = 0.f;
    for (unsigned j = b0; j < b1; ++j) {
        unsigned e = perm_c[j];
        int le = le_idx[e];
        float wt = S1[e] * invd;
        float2 av = *reinterpret_cast<const float2*>(A + (size_t)le * DIM + d);
        ax = fmaf(wt, av.x, ax);
        ay = fmaf(wt, av.y, ay);
    }
    *reinterpret_cast<float2*>(AGC + (size_t)w * DIM + d) = make_float2(ax, ay);
}

// wave per literal: AGL[l] = sum_e w2[e] * B[ce[e]], w2 normalized by D2[ce[e]]
__launch_bounds__(256)
__global__ void aggr_l(const unsigned* __restrict__ base_l, const unsigned* __restrict__ perm_l,
                       const int* __restrict__ ce_idx,
                       const float* __restrict__ S2, const float* __restrict__ D2,
                       const float* __restrict__ Bm, float* __restrict__ AGL)
{
    int w = (int)((blockIdx.x * (size_t)blockDim.x + threadIdx.x) >> 6);
    if (w >= LSZ) return;
    int lane = threadIdx.x & 63;
    int d = lane * 2;
    unsigned b0 = base_l[w], b1 = base_l[w + 1];
    float ax = 0.f, ay = 0.f;
    for (unsigned j = b0; j < b1; ++j) {
        unsigned e = perm_l[j];
        int ce = ce_idx[e];
        float wt = S2[e] / (D2[ce] + 1e-16f);
        float2 bv = *reinterpret_cast<const float2*>(Bm + (size_t)ce * DIM + d);
        ax = fmaf(wt, bv.x, ax);
        ay = fmaf(wt, bv.y, ay);
    }
    *reinterpret_cast<float2*>(AGL + (size_t)w * DIM + d) = make_float2(ax, ay);
}

extern "C" void kernel_launch(void* const* d_in, const int* in_sizes, int n_in,
                              void* d_out, int out_size, void* d_ws, size_t ws_size,
                              hipStream_t stream)
{
    const int*   le      = (const int*)  d_in[2];
    const int*   ce      = (const int*)  d_in[3];
    const float* l_emb0  = (const float*)d_in[4];
    const float* c_emb0  = (const float*)d_in[5];
    const float* l2c_w1  = (const float*)d_in[6];
    const float* l2c_b1  = (const float*)d_in[7];
    const float* l2c_w2  = (const float*)d_in[8];
    const float* l2c_b2  = (const float*)d_in[9];
    const float* c2l_w1  = (const float*)d_in[10];
    const float* c2l_b1  = (const float*)d_in[11];
    const float* c2l_w2  = (const float*)d_in[12];
    const float* c2l_b2  = (const float*)d_in[13];
    const float* l2l_w1  = (const float*)d_in[14];
    const float* l2l_b1  = (const float*)d_in[15];
    const float* l2l_w2  = (const float*)d_in[16];
    const float* l2l_b2  = (const float*)d_in[17];
    const float* c_att   = (const float*)d_in[18];
    const float* c_upd_w = (const float*)d_in[19];
    const float* c_upd_b = (const float*)d_in[20];
    const float* l_att   = (const float*)d_in[21];
    const float* l_upd_w = (const float*)d_in[22];
    const float* l_upd_b = (const float*)d_in[23];

    float* out = (float*)d_out;
    float* outL[3] = { out,
                       out + (size_t)LSZ * DIM,
                       out + 2 * (size_t)LSZ * DIM };
    float* outC[3] = { out + 3 * (size_t)LSZ * DIM,
                       out + 3 * (size_t)LSZ * DIM + (size_t)CSZ * DIM,
                       out + 3 * (size_t)LSZ * DIM + 2 * (size_t)CSZ * DIM };

    float* ws  = (float*)d_ws;
    float* A    = ws;                          // L*128
    float* Bm   = A    + (size_t)LSZ * DIM;    // C*128
    float* AGC  = Bm   + (size_t)CSZ * DIM;    // C*128
    float* AGL  = AGC  + (size_t)CSZ * DIM;    // L*128
    float* S1   = AGL  + (size_t)LSZ * DIM;    // E
    float* S2   = S1   + ESZ;                  // E
    float* pc1  = S2   + ESZ;                  // C
    float* qc2  = pc1  + CSZ;                  // C
    float* ql1  = qc2  + CSZ;                  // L
    float* pl2  = ql1  + LSZ;                  // L
    float* D1   = pl2  + LSZ;                  // C
    float* D2   = D1   + CSZ;                  // C
    unsigned* base_c = (unsigned*)(D2 + CSZ);  // C+1
    unsigned* base_l = base_c + (CSZ + 1);     // L+1
    unsigned* cnt_c  = base_l + (LSZ + 1);     // C (reused as cursor)
    unsigned* cnt_l  = cnt_c + CSZ;            // L (reused as cursor)
    unsigned* perm_c = cnt_l + LSZ;            // E
    unsigned* perm_l = perm_c + ESZ;           // E
    unsigned* bsum   = perm_l + ESZ;           // 1024

    // output slot 0 = input embeddings
    hipMemcpyAsync(outL[0], l_emb0, (size_t)LSZ * DIM * sizeof(float),
                   hipMemcpyDeviceToDevice, stream);
    hipMemcpyAsync(outC[0], c_emb0, (size_t)CSZ * DIM * sizeof(float),
                   hipMemcpyDeviceToDevice, stream);

    const int GL = (LSZ + 63) / 64;
    const int GC = (CSZ + 63) / 64;
    const int GE_THR = (ESZ + 255) / 256;
    const int GC_THR = (CSZ + 255) / 256;
    const int GC_WAVE = (CSZ + 3) / 4;
    const int GL_WAVE = (LSZ + 3) / 4;

    // ---- CSR build (graph is constant across both iterations) ----
    hipMemsetAsync(cnt_c, 0, CSZ * sizeof(unsigned), stream);
    hipMemsetAsync(cnt_l, 0, LSZ * sizeof(unsigned), stream);
    hist_kernel<<<GE_THR, 256, 0, stream>>>(le, ce, cnt_c, cnt_l);

    int nb_c = (CSZ + 1023) / 1024;
    int nb_l = (LSZ + 1023) / 1024;
    scan_partial<<<nb_c, 256, 0, stream>>>(cnt_c, base_c, bsum, CSZ);
    scan_top<<<1, 256, 0, stream>>>(bsum, nb_c);
    scan_add<<<(CSZ + 255) / 256, 256, 0, stream>>>(base_c, bsum, CSZ, ESZ);
    scan_partial<<<nb_l, 256, 0, stream>>>(cnt_l, base_l, bsum, LSZ);
    scan_top<<<1, 256, 0, stream>>>(bsum, nb_l);
    scan_add<<<(LSZ + 255) / 256, 256, 0, stream>>>(base_l, bsum, LSZ, ESZ);

    // cursors = copy of bases
    hipMemcpyAsync(cnt_c, base_c, CSZ * sizeof(unsigned), hipMemcpyDeviceToDevice, stream);
    hipMemcpyAsync(cnt_l, base_l, LSZ * sizeof(unsigned), hipMemcpyDeviceToDevice, stream);
    scatter_kernel<<<GE_THR, 256, 0, stream>>>(le, ce, cnt_c, cnt_l, perm_c, perm_l);

    for (int it = 0; it < 2; ++it) {
        const float* l_in = (it == 0) ? l_emb0 : outL[1];
        const float* c_in = (it == 0) ? c_emb0 : outC[1];
        float* l_out = outL[it + 1];
        float* c_out = outC[it + 1];

        // l_msg_feat = MLP2(l_in) -> A ; c_msg_feat = MLP2(c_in) -> Bm
        gemm128<1, true,  false><<<GL, 256, 0, stream>>>(l_in, l2c_w1, nullptr, nullptr, nullptr, nullptr, l2c_b1, A, LSZ);
        gemm128<1, false, false><<<GL, 256, 0, stream>>>(A,    l2c_w2, nullptr, nullptr, nullptr, nullptr, l2c_b2, A, LSZ);
        gemm128<1, true,  false><<<GC, 256, 0, stream>>>(c_in, c2l_w1, nullptr, nullptr, nullptr, nullptr, c2l_b1, Bm, CSZ);
        gemm128<1, false, false><<<GC, 256, 0, stream>>>(Bm,   c2l_w2, nullptr, nullptr, nullptr, nullptr, c2l_b2, Bm, CSZ);

        // attention scores via per-node dots
        gemv_c<<<GC_WAVE, 256, 0, stream>>>(c_in, Bm, c_att, l_att, pc1, qc2);
        gemv_l<<<GL_WAVE, 256, 0, stream>>>(l_in, A, c_att, l_att, ql1, pl2);
        edge_score<<<GE_THR, 256, 0, stream>>>(le, ce, pc1, ql1, pl2, qc2, S1, S2);

        // segment softmax over ce (both, faithful to reference)
        seg_softmax<<<GC_THR, 256, 0, stream>>>(base_c, perm_c, S1, S2, D1, D2);

        // aggregation (no atomics, each output row written once)
        aggr_c<<<GC_WAVE, 256, 0, stream>>>(base_c, perm_c, le, S1, D1, A, AGC);
        aggr_l<<<GL_WAVE, 256, 0, stream>>>(base_l, perm_l, ce, S2, D2, Bm, AGL);

        // l2l_msg = MLP2(pair-swapped l_in) -> A (A free after aggr_c)
        gemm128<1, true,  true ><<<GL, 256, 0, stream>>>(l_in, l2l_w1, nullptr, nullptr, nullptr, nullptr, l2l_b1, A, LSZ);
        gemm128<1, false, false><<<GL, 256, 0, stream>>>(A,    l2l_w2, nullptr, nullptr, nullptr, nullptr, l2l_b2, A, LSZ);

        // c_out = [c_in, AGC] @ c_upd_w + b
        gemm128<2, false, false><<<GC, 256, 0, stream>>>(c_in, c_upd_w, AGC, c_upd_w + DIM * DIM,
                                                         nullptr, nullptr, c_upd_b, c_out, CSZ);
        // l_out = [l_in, AGL, l2l_msg] @ l_upd_w + b
        gemm128<3, false, false><<<GL, 256, 0, stream>>>(l_in, l_upd_w, AGL, l_upd_w + DIM * DIM,
                                                         A, l_upd_w + 2 * DIM * DIM, l_upd_b, l_out, LSZ);
    }
}

// Round 3
// 1420.295 us; speedup vs baseline: 3.0833x; 1.8398x over previous
//
#include <hip/hip_runtime.h>

#define DIM 128
#define LSZ 100000
#define CSZ 210000
#define ESZ 630000
#define CH  16384   // ushorts per 128x128 weight chunk

typedef __attribute__((ext_vector_type(8))) short short8;
typedef __attribute__((ext_vector_type(4))) float f32x4;

__device__ __forceinline__ ushort f2b(float x) {          // fp32 -> bf16 RNE
    unsigned u = __float_as_uint(x);
    return (ushort)((u + 0x7FFFu + ((u >> 16) & 1)) >> 16);
}
__device__ __forceinline__ float b2f(unsigned lo16) {     // bf16 (low bits) -> fp32
    return __uint_as_float(lo16 << 16);
}
// swizzled byte offset of 16B chunk `c` (0..15) in row `row` of a [128][128]bf16 LDS tile
__device__ __forceinline__ int lds_off(int row, int c) {
    return row * 256 + ((c ^ (row & 7)) << 4);
}

// shared K=128 inner loop: 4 k-steps x 16 MFMA, A from Xs rows, B from Ws rows (Wt layout)
__device__ __forceinline__ void kloop128(const char* Xs, const char* Ws,
                                         int wr, int wc, int lane, f32x4 (&acc)[4][4])
{
    #pragma unroll
    for (int ks = 0; ks < 4; ++ks) {
        int kc = ks * 4 + (lane >> 4);
        short8 af[4], bfr[4];
        #pragma unroll
        for (int m = 0; m < 4; ++m) {
            int row = wr * 64 + m * 16 + (lane & 15);
            af[m] = *(const short8*)(Xs + lds_off(row, kc));
        }
        #pragma unroll
        for (int n = 0; n < 4; ++n) {
            int col = wc * 64 + n * 16 + (lane & 15);
            bfr[n] = *(const short8*)(Ws + lds_off(col, kc));
        }
        #pragma unroll
        for (int m = 0; m < 4; ++m)
            #pragma unroll
            for (int n = 0; n < 4; ++n)
                acc[m][n] = __builtin_amdgcn_mfma_f32_16x16x32_bf16(af[m], bfr[n], acc[m][n], 0, 0, 0);
    }
}

// ---------------------------------------------------------------------------
// Fused 2-layer MLP: Yb = bf16( relu(X@W1+b1) @ W2 + b2 ), X bf16, W transposed bf16.
// Hidden tile kept in LDS. SWAP: X row gr read from gr^1 (literal pair swap).
// ---------------------------------------------------------------------------
template<bool SWAP>
__launch_bounds__(256)
__global__ void mlp2_fused(const ushort* __restrict__ X,
                           const ushort* __restrict__ Wt1, const ushort* __restrict__ Wt2,
                           const float* __restrict__ b1, const float* __restrict__ b2,
                           ushort* __restrict__ Yb, int M)
{
    __shared__ char smem[65536];
    char* Xs = smem;
    char* Ws = smem + 32768;
    const int tid  = threadIdx.x;
    const int lane = tid & 63;
    const int wid  = tid >> 6;
    const int wr = wid >> 1, wc = wid & 1;
    const int r0t = blockIdx.x * 128;

    #pragma unroll
    for (int i = 0; i < 8; ++i) {
        int id = i * 256 + tid;
        int row = id >> 4, c = id & 15;
        int gr = r0t + row;
        short8 v = {0,0,0,0,0,0,0,0};
        if (gr < M) {
            int sr = SWAP ? (gr ^ 1) : gr;
            v = *(const short8*)(X + (size_t)sr * DIM + c * 8);
        }
        *(short8*)(Xs + lds_off(row, c)) = v;
        *(short8*)(Ws + lds_off(row, c)) = *(const short8*)(Wt1 + row * DIM + c * 8);
    }
    __syncthreads();

    f32x4 acc[4][4];
    #pragma unroll
    for (int m = 0; m < 4; ++m)
        #pragma unroll
        for (int n = 0; n < 4; ++n) acc[m][n] = (f32x4){0.f, 0.f, 0.f, 0.f};

    kloop128(Xs, Ws, wr, wc, lane, acc);
    __syncthreads();                       // all LDS reads of X/W1 done

    // stage W2; write H = relu(acc+b1) as bf16 into Xs (swizzled scalar writes)
    #pragma unroll
    for (int i = 0; i < 8; ++i) {
        int id = i * 256 + tid;
        int row = id >> 4, c = id & 15;
        *(short8*)(Ws + lds_off(row, c)) = *(const short8*)(Wt2 + row * DIM + c * 8);
    }
    {
        const int col0 = wc * 64 + (lane & 15);
        float b1v[4];
        #pragma unroll
        for (int n = 0; n < 4; ++n) b1v[n] = b1[col0 + n * 16];
        #pragma unroll
        for (int m = 0; m < 4; ++m)
            #pragma unroll
            for (int i = 0; i < 4; ++i) {
                int row = wr * 64 + m * 16 + (lane >> 4) * 4 + i;
                #pragma unroll
                for (int n = 0; n < 4; ++n) {
                    float v = fmaxf(acc[m][n][i] + b1v[n], 0.f);
                    int cb = (col0 + n * 16) * 2;
                    *(ushort*)(Xs + row * 256 + (((cb >> 4) ^ (row & 7)) << 4) + (cb & 15)) = f2b(v);
                }
            }
    }
    __syncthreads();

    #pragma unroll
    for (int m = 0; m < 4; ++m)
        #pragma unroll
        for (int n = 0; n < 4; ++n) acc[m][n] = (f32x4){0.f, 0.f, 0.f, 0.f};

    kloop128(Xs, Ws, wr, wc, lane, acc);

    const int col0 = wc * 64 + (lane & 15);
    float b2v[4];
    #pragma unroll
    for (int n = 0; n < 4; ++n) b2v[n] = b2[col0 + n * 16];
    #pragma unroll
    for (int m = 0; m < 4; ++m)
        #pragma unroll
        for (int i = 0; i < 4; ++i) {
            int gr = r0t + wr * 64 + m * 16 + (lane >> 4) * 4 + i;
            if (gr < M) {
                #pragma unroll
                for (int n = 0; n < 4; ++n)
                    Yb[(size_t)gr * DIM + col0 + n * 16] = f2b(acc[m][n][i] + b2v[n]);
            }
        }
}

// ---------------------------------------------------------------------------
// Update GEMM: Y = concat_K(X1..XNIN) @ W + bias; writes fp32 (d_out) + bf16 (next iter)
// ---------------------------------------------------------------------------
template<int NIN>
__launch_bounds__(256)
__global__ void upd_gemm(const ushort* __restrict__ X1, const ushort* __restrict__ X2,
                         const ushort* __restrict__ X3,
                         const ushort* __restrict__ Wt, const float* __restrict__ bias,
                         float* __restrict__ Yf, ushort* __restrict__ Yb, int M)
{
    __shared__ char smem[65536];
    char* Xs = smem;
    char* Ws = smem + 32768;
    const int tid  = threadIdx.x;
    const int lane = tid & 63;
    const int wid  = tid >> 6;
    const int wr = wid >> 1, wc = wid & 1;
    const int r0t = blockIdx.x * 128;

    f32x4 acc[4][4];
    #pragma unroll
    for (int m = 0; m < 4; ++m)
        #pragma unroll
        for (int n = 0; n < 4; ++n) acc[m][n] = (f32x4){0.f, 0.f, 0.f, 0.f};

    #pragma unroll
    for (int in = 0; in < NIN; ++in) {
        const ushort* X = (in == 0) ? X1 : ((in == 1) ? X2 : X3);
        __syncthreads();
        #pragma unroll
        for (int i = 0; i < 8; ++i) {
            int id = i * 256 + tid;
            int row = id >> 4, c = id & 15;
            int gr = r0t + row;
            short8 v = {0,0,0,0,0,0,0,0};
            if (gr < M) v = *(const short8*)(X + (size_t)gr * DIM + c * 8);
            *(short8*)(Xs + lds_off(row, c)) = v;
            *(short8*)(Ws + lds_off(row, c)) =
                *(const short8*)(Wt + (size_t)in * CH + row * DIM + c * 8);
        }
        __syncthreads();
        kloop128(Xs, Ws, wr, wc, lane, acc);
    }

    const int col0 = wc * 64 + (lane & 15);
    float bv[4];
    #pragma unroll
    for (int n = 0; n < 4; ++n) bv[n] = bias[col0 + n * 16];
    #pragma unroll
    for (int m = 0; m < 4; ++m)
        #pragma unroll
        for (int i = 0; i < 4; ++i) {
            int gr = r0t + wr * 64 + m * 16 + (lane >> 4) * 4 + i;
            if (gr < M) {
                #pragma unroll
                for (int n = 0; n < 4; ++n) {
                    float v = acc[m][n][i] + bv[n];
                    Yf[(size_t)gr * DIM + col0 + n * 16] = v;
                    Yb[(size_t)gr * DIM + col0 + n * 16] = f2b(v);
                }
            }
        }
}

// ---------------------------------------------------------------------------
// one-time converts: weights (transpose+bf16), embeddings (bf16 + fp32 out slot 0)
// ---------------------------------------------------------------------------
__launch_bounds__(256)
__global__ void wtrans(const float* __restrict__ W, ushort* __restrict__ Wt)
{
    int ch  = blockIdx.y;
    int idx = blockIdx.x * 256 + threadIdx.x;      // 0..16383
    int k = idx >> 7, c = idx & 127;
    float v = W[((size_t)ch * 128 + k) * 128 + c];
    Wt[(size_t)ch * CH + c * 128 + k] = f2b(v);
}

__launch_bounds__(256)
__global__ void cvt_copy(const float* __restrict__ in, ushort* __restrict__ out_bf,
                         float* __restrict__ out_f32, int n8)
{
    int i = blockIdx.x * 256 + threadIdx.x;
    if (i >= n8) return;
    const float4* p = (const float4*)in + (size_t)i * 2;
    float4 a = p[0], b = p[1];
    ((float4*)out_f32)[(size_t)i * 2]     = a;
    ((float4*)out_f32)[(size_t)i * 2 + 1] = b;
    ushort r[8] = {f2b(a.x), f2b(a.y), f2b(a.z), f2b(a.w),
                   f2b(b.x), f2b(b.y), f2b(b.z), f2b(b.w)};
    *(short8*)(out_bf + (size_t)i * 8) = *(short8*)r;
}

// ---------------------------------------------------------------------------
// CSR build: histogram -> exclusive scan -> scatter
// ---------------------------------------------------------------------------
__launch_bounds__(256)
__global__ void hist_kernel(const int* __restrict__ le, const int* __restrict__ ce,
                            unsigned* __restrict__ cnt_c, unsigned* __restrict__ cnt_l)
{
    int e = blockIdx.x * blockDim.x + threadIdx.x;
    if (e >= ESZ) return;
    atomicAdd(cnt_c + ce[e], 1u);
    atomicAdd(cnt_l + le[e], 1u);
}

__launch_bounds__(256)
__global__ void scan_partial(const unsigned* __restrict__ in, unsigned* __restrict__ out,
                             unsigned* __restrict__ bsum, int n)
{
    __shared__ unsigned s[256];
    int tid  = threadIdx.x;
    int base = blockIdx.x * 1024 + tid * 4;
    unsigned v[4];
    #pragma unroll
    for (int k = 0; k < 4; ++k) v[k] = (base + k < n) ? in[base + k] : 0u;
    unsigned tsum = v[0] + v[1] + v[2] + v[3];
    s[tid] = tsum;
    __syncthreads();
    for (int off = 1; off < 256; off <<= 1) {
        unsigned t = (tid >= off) ? s[tid - off] : 0u;
        __syncthreads();
        s[tid] += t;
        __syncthreads();
    }
    unsigned run = s[tid] - tsum;
    #pragma unroll
    for (int k = 0; k < 4; ++k) {
        if (base + k < n) out[base + k] = run;
        run += v[k];
    }
    if (tid == 255) bsum[blockIdx.x] = s[255];
}

__launch_bounds__(256)
__global__ void scan_top(unsigned* __restrict__ bsum, int nb)
{
    __shared__ unsigned s[256];
    int tid = threadIdx.x;
    unsigned v = (tid < nb) ? bsum[tid] : 0u;
    s[tid] = v;
    __syncthreads();
    for (int off = 1; off < 256; off <<= 1) {
        unsigned t = (tid >= off) ? s[tid - off] : 0u;
        __syncthreads();
        s[tid] += t;
        __syncthreads();
    }
    if (tid < nb) bsum[tid] = s[tid] - v;
}

__launch_bounds__(256)
__global__ void scan_add(unsigned* __restrict__ out, const unsigned* __restrict__ bsum,
                         int n, unsigned total)
{
    int i = blockIdx.x * blockDim.x + threadIdx.x;
    if (i < n) out[i] += bsum[i >> 10];
    if (i == 0) out[n] = total;
}

__launch_bounds__(256)
__global__ void scatter_kernel(const int* __restrict__ le, const int* __restrict__ ce,
                               unsigned* __restrict__ cur_c, unsigned* __restrict__ cur_l,
                               unsigned* __restrict__ perm_c, unsigned* __restrict__ perm_l)
{
    int e = blockIdx.x * blockDim.x + threadIdx.x;
    if (e >= ESZ) return;
    unsigned p1 = atomicAdd(cur_c + ce[e], 1u);
    perm_c[p1] = (unsigned)e;
    unsigned p2 = atomicAdd(cur_l + le[e], 1u);
    perm_l[p2] = (unsigned)e;
}

// ---------------------------------------------------------------------------
// attention: per-node dots (bf16 inputs), per-edge score, segment softmax, aggregation
// ---------------------------------------------------------------------------
__launch_bounds__(256)
__global__ void gemv_c(const ushort* __restrict__ c_bf, const ushort* __restrict__ B_bf,
                       const float* __restrict__ c_att, const float* __restrict__ l_att,
                       float* __restrict__ pc1, float* __restrict__ qc2)
{
    int w = (int)((blockIdx.x * (size_t)blockDim.x + threadIdx.x) >> 6);
    if (w >= CSZ) return;
    int lane = threadIdx.x & 63;
    int d = lane * 2;
    unsigned cv = *(const unsigned*)(c_bf + (size_t)w * DIM + d);
    unsigned bv = *(const unsigned*)(B_bf + (size_t)w * DIM + d);
    float2 a1 = *(const float2*)(c_att + d);
    float2 a2 = *(const float2*)(l_att + DIM + d);
    float s1 = b2f(cv & 0xffffu) * a1.x + b2f(cv >> 16) * a1.y;
    float s2 = b2f(bv & 0xffffu) * a2.x + b2f(bv >> 16) * a2.y;
    #pragma unroll
    for (int m = 32; m >= 1; m >>= 1) {
        s1 += __shfl_xor(s1, m);
        s2 += __shfl_xor(s2, m);
    }
    if (lane == 0) { pc1[w] = s1; qc2[w] = s2; }
}

__launch_bounds__(256)
__global__ void gemv_l(const ushort* __restrict__ l_bf, const ushort* __restrict__ A_bf,
                       const float* __restrict__ c_att, const float* __restrict__ l_att,
                       float* __restrict__ ql1, float* __restrict__ pl2)
{
    int w = (int)((blockIdx.x * (size_t)blockDim.x + threadIdx.x) >> 6);
    if (w >= LSZ) return;
    int lane = threadIdx.x & 63;
    int d = lane * 2;
    unsigned av = *(const unsigned*)(A_bf + (size_t)w * DIM + d);
    unsigned lv = *(const unsigned*)(l_bf + (size_t)w * DIM + d);
    float2 a1 = *(const float2*)(c_att + DIM + d);
    float2 a2 = *(const float2*)(l_att + d);
    float s1 = b2f(av & 0xffffu) * a1.x + b2f(av >> 16) * a1.y;
    float s2 = b2f(lv & 0xffffu) * a2.x + b2f(lv >> 16) * a2.y;
    #pragma unroll
    for (int m = 32; m >= 1; m >>= 1) {
        s1 += __shfl_xor(s1, m);
        s2 += __shfl_xor(s2, m);
    }
    if (lane == 0) { ql1[w] = s1; pl2[w] = s2; }
}

__launch_bounds__(256)
__global__ void edge_score(const int* __restrict__ le_idx, const int* __restrict__ ce_idx,
                           const float* __restrict__ pc1, const float* __restrict__ ql1,
                           const float* __restrict__ pl2, const float* __restrict__ qc2,
                           float* __restrict__ S1, float* __restrict__ S2)
{
    int e = blockIdx.x * blockDim.x + threadIdx.x;
    if (e >= ESZ) return;
    int le = le_idx[e], ce = ce_idx[e];
    float s1 = pc1[ce] + ql1[le];
    float s2 = pl2[le] + qc2[ce];
    s1 = (s1 > 0.f) ? s1 : 0.2f * s1;
    s2 = (s2 > 0.f) ? s2 : 0.2f * s2;
    S1[e] = s1;
    S2[e] = s2;
}

__launch_bounds__(256)
__global__ void seg_softmax(const unsigned* __restrict__ base_c, const unsigned* __restrict__ perm_c,
                            float* __restrict__ S1, float* __restrict__ S2,
                            float* __restrict__ D1, float* __restrict__ D2)
{
    int c = blockIdx.x * blockDim.x + threadIdx.x;
    if (c >= CSZ) return;
    unsigned b0 = base_c[c], b1 = base_c[c + 1];
    float m1 = -1e30f, m2 = -1e30f;
    for (unsigned j = b0; j < b1; ++j) {
        unsigned e = perm_c[j];
        m1 = fmaxf(m1, S1[e]);
        m2 = fmaxf(m2, S2[e]);
    }
    float d1 = 0.f, d2 = 0.f;
    for (unsigned j = b0; j < b1; ++j) {
        unsigned e = perm_c[j];
        float ex1 = __expf(S1[e] - m1);
        float ex2 = __expf(S2[e] - m2);
        S1[e] = ex1; S2[e] = ex2;
        d1 += ex1; d2 += ex2;
    }
    D1[c] = d1; D2[c] = d2;
}

__launch_bounds__(256)
__global__ void aggr_c(const unsigned* __restrict__ base_c, const unsigned* __restrict__ perm_c,
                       const int* __restrict__ le_idx,
                       const float* __restrict__ S1, const float* __restrict__ D1,
                       const ushort* __restrict__ A_bf, ushort* __restrict__ AGC)
{
    int w = (int)((blockIdx.x * (size_t)blockDim.x + threadIdx.x) >> 6);
    if (w >= CSZ) return;
    int lane = threadIdx.x & 63;
    int d = lane * 2;
    unsigned b0 = base_c[w], b1 = base_c[w + 1];
    float invd = 1.f / (D1[w] + 1e-16f);
    float ax = 0.f, ay = 0.f;
    for (unsigned j = b0; j < b1; ++j) {
        unsigned e = perm_c[j];
        int le = le_idx[e];
        float wt = S1[e] * invd;
        unsigned av = *(const unsigned*)(A_bf + (size_t)le * DIM + d);
        ax = fmaf(wt, b2f(av & 0xffffu), ax);
        ay = fmaf(wt, b2f(av >> 16), ay);
    }
    *(unsigned*)(AGC + (size_t)w * DIM + d) = (unsigned)f2b(ax) | ((unsigned)f2b(ay) << 16);
}

__launch_bounds__(256)
__global__ void aggr_l(const unsigned* __restrict__ base_l, const unsigned* __restrict__ perm_l,
                       const int* __restrict__ ce_idx,
                       const float* __restrict__ S2, const float* __restrict__ D2,
                       const ushort* __restrict__ B_bf, ushort* __restrict__ AGL)
{
    int w = (int)((blockIdx.x * (size_t)blockDim.x + threadIdx.x) >> 6);
    if (w >= LSZ) return;
    int lane = threadIdx.x & 63;
    int d = lane * 2;
    unsigned b0 = base_l[w], b1 = base_l[w + 1];
    float ax = 0.f, ay = 0.f;
    for (unsigned j = b0; j < b1; ++j) {
        unsigned e = perm_l[j];
        int ce = ce_idx[e];
        float wt = S2[e] / (D2[ce] + 1e-16f);
        unsigned bv = *(const unsigned*)(B_bf + (size_t)ce * DIM + d);
        ax = fmaf(wt, b2f(bv & 0xffffu), ax);
        ay = fmaf(wt, b2f(bv >> 16), ay);
    }
    *(unsigned*)(AGL + (size_t)w * DIM + d) = (unsigned)f2b(ax) | ((unsigned)f2b(ay) << 16);
}

extern "C" void kernel_launch(void* const* d_in, const int* in_sizes, int n_in,
                              void* d_out, int out_size, void* d_ws, size_t ws_size,
                              hipStream_t stream)
{
    const int*   le      = (const int*)  d_in[2];
    const int*   ce      = (const int*)  d_in[3];
    const float* l_emb0  = (const float*)d_in[4];
    const float* c_emb0  = (const float*)d_in[5];
    const float* l2c_w1  = (const float*)d_in[6];
    const float* l2c_b1  = (const float*)d_in[7];
    const float* l2c_w2  = (const float*)d_in[8];
    const float* l2c_b2  = (const float*)d_in[9];
    const float* c2l_w1  = (const float*)d_in[10];
    const float* c2l_b1  = (const float*)d_in[11];
    const float* c2l_w2  = (const float*)d_in[12];
    const float* c2l_b2  = (const float*)d_in[13];
    const float* l2l_w1  = (const float*)d_in[14];
    const float* l2l_b1  = (const float*)d_in[15];
    const float* l2l_w2  = (const float*)d_in[16];
    const float* l2l_b2  = (const float*)d_in[17];
    const float* c_att   = (const float*)d_in[18];
    const float* c_upd_w = (const float*)d_in[19];
    const float* c_upd_b = (const float*)d_in[20];
    const float* l_att   = (const float*)d_in[21];
    const float* l_upd_w = (const float*)d_in[22];
    const float* l_upd_b = (const float*)d_in[23];

    float* out = (float*)d_out;
    float* outL[3] = { out,
                       out + (size_t)LSZ * DIM,
                       out + 2 * (size_t)LSZ * DIM };
    float* outC[3] = { out + 3 * (size_t)LSZ * DIM,
                       out + 3 * (size_t)LSZ * DIM + (size_t)CSZ * DIM,
                       out + 3 * (size_t)LSZ * DIM + 2 * (size_t)CSZ * DIM };

    // workspace layout (16B-aligned bf16 row buffers first)
    char* p = (char*)d_ws;
    ushort* A_bf   = (ushort*)p; p += (size_t)LSZ * DIM * 2;
    ushort* B_bf   = (ushort*)p; p += (size_t)CSZ * DIM * 2;
    ushort* AGC_bf = (ushort*)p; p += (size_t)CSZ * DIM * 2;
    ushort* AGL_bf = (ushort*)p; p += (size_t)LSZ * DIM * 2;
    ushort* l_bf0  = (ushort*)p; p += (size_t)LSZ * DIM * 2;
    ushort* l_bf1  = (ushort*)p; p += (size_t)LSZ * DIM * 2;
    ushort* c_bf0  = (ushort*)p; p += (size_t)CSZ * DIM * 2;
    ushort* c_bf1  = (ushort*)p; p += (size_t)CSZ * DIM * 2;
    ushort* Wt     = (ushort*)p; p += (size_t)11 * CH * 2;
    float* S1  = (float*)p; p += (size_t)ESZ * 4;
    float* S2  = (float*)p; p += (size_t)ESZ * 4;
    float* pc1 = (float*)p; p += (size_t)CSZ * 4;
    float* qc2 = (float*)p; p += (size_t)CSZ * 4;
    float* ql1 = (float*)p; p += (size_t)LSZ * 4;
    float* pl2 = (float*)p; p += (size_t)LSZ * 4;
    float* D1  = (float*)p; p += (size_t)CSZ * 4;
    float* D2  = (float*)p; p += (size_t)CSZ * 4;
    unsigned* base_c = (unsigned*)p; p += (size_t)(CSZ + 1) * 4;
    unsigned* base_l = (unsigned*)p; p += (size_t)(LSZ + 1) * 4;
    unsigned* cnt_c  = (unsigned*)p; p += (size_t)CSZ * 4;
    unsigned* cnt_l  = (unsigned*)p; p += (size_t)LSZ * 4;
    unsigned* perm_c = (unsigned*)p; p += (size_t)ESZ * 4;
    unsigned* perm_l = (unsigned*)p; p += (size_t)ESZ * 4;
    unsigned* bsum   = (unsigned*)p; p += 1024 * 4;

    const int GL128 = (LSZ + 127) / 128;
    const int GC128 = (CSZ + 127) / 128;
    const int GE_THR = (ESZ + 255) / 256;
    const int GC_THR = (CSZ + 255) / 256;
    const int GC_WAVE = (CSZ + 3) / 4;
    const int GL_WAVE = (LSZ + 3) / 4;

    // one-time converts: embeddings -> bf16 + fp32 output slot 0; weights -> bf16 transposed
    cvt_copy<<<(LSZ * 16 + 255) / 256, 256, 0, stream>>>(l_emb0, l_bf0, outL[0], LSZ * 16);
    cvt_copy<<<(CSZ * 16 + 255) / 256, 256, 0, stream>>>(c_emb0, c_bf0, outC[0], CSZ * 16);
    wtrans<<<dim3(64, 1), 256, 0, stream>>>(l2c_w1, Wt + 0 * CH);
    wtrans<<<dim3(64, 1), 256, 0, stream>>>(l2c_w2, Wt + 1 * CH);
    wtrans<<<dim3(64, 1), 256, 0, stream>>>(c2l_w1, Wt + 2 * CH);
    wtrans<<<dim3(64, 1), 256, 0, stream>>>(c2l_w2, Wt + 3 * CH);
    wtrans<<<dim3(64, 1), 256, 0, stream>>>(l2l_w1, Wt + 4 * CH);
    wtrans<<<dim3(64, 1), 256, 0, stream>>>(l2l_w2, Wt + 5 * CH);
    wtrans<<<dim3(64, 2), 256, 0, stream>>>(c_upd_w, Wt + 6 * CH);
    wtrans<<<dim3(64, 3), 256, 0, stream>>>(l_upd_w, Wt + 8 * CH);

    // CSR build (graph constant across iterations)
    hipMemsetAsync(cnt_c, 0, CSZ * sizeof(unsigned), stream);
    hipMemsetAsync(cnt_l, 0, LSZ * sizeof(unsigned), stream);
    hist_kernel<<<GE_THR, 256, 0, stream>>>(le, ce, cnt_c, cnt_l);
    int nb_c = (CSZ + 1023) / 1024;
    int nb_l = (LSZ + 1023) / 1024;
    scan_partial<<<nb_c, 256, 0, stream>>>(cnt_c, base_c, bsum, CSZ);
    scan_top<<<1, 256, 0, stream>>>(bsum, nb_c);
    scan_add<<<(CSZ + 255) / 256, 256, 0, stream>>>(base_c, bsum, CSZ, ESZ);
    scan_partial<<<nb_l, 256, 0, stream>>>(cnt_l, base_l, bsum, LSZ);
    scan_top<<<1, 256, 0, stream>>>(bsum, nb_l);
    scan_add<<<(LSZ + 255) / 256, 256, 0, stream>>>(base_l, bsum, LSZ, ESZ);
    hipMemcpyAsync(cnt_c, base_c, CSZ * sizeof(unsigned), hipMemcpyDeviceToDevice, stream);
    hipMemcpyAsync(cnt_l, base_l, LSZ * sizeof(unsigned), hipMemcpyDeviceToDevice, stream);
    scatter_kernel<<<GE_THR, 256, 0, stream>>>(le, ce, cnt_c, cnt_l, perm_c, perm_l);

    for (int it = 0; it < 2; ++it) {
        const ushort* l_in = (it == 0) ? l_bf0 : l_bf1;
        const ushort* c_in = (it == 0) ? c_bf0 : c_bf1;

        // message MLPs (fused 2-layer, bf16 MFMA)
        mlp2_fused<false><<<GL128, 256, 0, stream>>>(l_in, Wt + 0 * CH, Wt + 1 * CH,
                                                     l2c_b1, l2c_b2, A_bf, LSZ);
        mlp2_fused<false><<<GC128, 256, 0, stream>>>(c_in, Wt + 2 * CH, Wt + 3 * CH,
                                                     c2l_b1, c2l_b2, B_bf, CSZ);

        // attention scores
        gemv_c<<<GC_WAVE, 256, 0, stream>>>(c_in, B_bf, c_att, l_att, pc1, qc2);
        gemv_l<<<GL_WAVE, 256, 0, stream>>>(l_in, A_bf, c_att, l_att, ql1, pl2);
        edge_score<<<GE_THR, 256, 0, stream>>>(le, ce, pc1, ql1, pl2, qc2, S1, S2);
        seg_softmax<<<GC_THR, 256, 0, stream>>>(base_c, perm_c, S1, S2, D1, D2);

        // aggregation (CSR, no atomics)
        aggr_c<<<GC_WAVE, 256, 0, stream>>>(base_c, perm_c, le, S1, D1, A_bf, AGC_bf);
        aggr_l<<<GL_WAVE, 256, 0, stream>>>(base_l, perm_l, ce, S2, D2, B_bf, AGL_bf);

        // l2l message (pair-swapped input), overwrites A_bf (consumed above)
        mlp2_fused<true><<<GL128, 256, 0, stream>>>(l_in, Wt + 4 * CH, Wt + 5 * CH,
                                                    l2l_b1, l2l_b2, A_bf, LSZ);

        // updates: fp32 to d_out + bf16 for next iteration
        upd_gemm<2><<<GC128, 256, 0, stream>>>(c_in, AGC_bf, nullptr,
                                               Wt + 6 * CH, c_upd_b, outC[it + 1], c_bf1, CSZ);
        upd_gemm<3><<<GL128, 256, 0, stream>>>(l_in, AGL_bf, A_bf,
                                               Wt + 8 * CH, l_upd_b, outL[it + 1], l_bf1, LSZ);
    }
}

// Round 5
// 1065.347 us; speedup vs baseline: 4.1105x; 1.3332x over previous
//
#include <hip/hip_runtime.h>

#define DIM 128
#define LSZ 100000
#define CSZ 210000
#define ESZ 630000
#define CH  16384   // ushorts per 128x128 weight chunk

typedef __attribute__((ext_vector_type(8))) short short8;
typedef __attribute__((ext_vector_type(4))) float f32x4;

__device__ __forceinline__ ushort f2b(float x) {          // fp32 -> bf16 RNE
    unsigned u = __float_as_uint(x);
    return (ushort)((u + 0x7FFFu + ((u >> 16) & 1)) >> 16);
}
__device__ __forceinline__ float b2f(unsigned lo16) {     // bf16 (low bits) -> fp32
    return __uint_as_float(lo16 << 16);
}
// swizzled byte offset of 16B chunk `c` (0..15) in row `row` of a [128][128]bf16 LDS tile
__device__ __forceinline__ int lds_off(int row, int c) {
    return row * 256 + ((c ^ (row & 7)) << 4);
}
// async global->LDS 16B: per-lane global src, wave-uniform LDS base (+lane*16 implicit)
__device__ __forceinline__ void gload_lds16(const void* g, void* l) {
    __builtin_amdgcn_global_load_lds(
        (const __attribute__((address_space(1))) unsigned*)g,
        (__attribute__((address_space(3))) unsigned*)l, 16, 0, 0);
}
// REQUIRED before any __syncthreads() that publishes LDS-DMA results: the barrier
// alone is not guaranteed to drain the async global_load_lds queue (cp.async rule).
__device__ __forceinline__ void vm_drain() {
    asm volatile("s_waitcnt vmcnt(0)" ::: "memory");
}

// shared K=128 inner loop: 4 k-steps x 16 MFMA
__device__ __forceinline__ void kloop128(const char* Xs, const char* Ws,
                                         int wr, int wc, int lane, f32x4 (&acc)[4][4])
{
    #pragma unroll
    for (int ks = 0; ks < 4; ++ks) {
        int kc = ks * 4 + (lane >> 4);
        short8 af[4], bfr[4];
        #pragma unroll
        for (int m = 0; m < 4; ++m) {
            int row = wr * 64 + m * 16 + (lane & 15);
            af[m] = *(const short8*)(Xs + lds_off(row, kc));
        }
        #pragma unroll
        for (int n = 0; n < 4; ++n) {
            int col = wc * 64 + n * 16 + (lane & 15);
            bfr[n] = *(const short8*)(Ws + lds_off(col, kc));
        }
        #pragma unroll
        for (int m = 0; m < 4; ++m)
            #pragma unroll
            for (int n = 0; n < 4; ++n)
                acc[m][n] = __builtin_amdgcn_mfma_f32_16x16x32_bf16(af[m], bfr[n], acc[m][n], 0, 0, 0);
    }
}

// stage a full 128x128 bf16 tile via global_load_lds, source pre-swizzled.
// SWAPROW: global row = base_row ^ 1 (within-tile literal pair swap).
template<bool SWAPROW>
__device__ __forceinline__ void stage_tile_fast(const ushort* __restrict__ G, size_t grow0,
                                                char* L, int wid, int lane)
{
    #pragma unroll
    for (int g = 0; g < 8; ++g) {
        int row0 = wid * 32 + g * 4;
        int row  = row0 + (lane >> 4);
        size_t grow = grow0 + (size_t)(SWAPROW ? (row ^ 1) : row);
        const ushort* src = G + grow * DIM + (((lane & 15) ^ (row & 7)) << 3);
        gload_lds16(src, L + row0 * 256);
    }
}

// ---------------------------------------------------------------------------
// Fused 2-layer MLP + optional per-row attention dot of the fp32 output.
// ---------------------------------------------------------------------------
template<bool SWAP, bool DOT>
__launch_bounds__(256)
__global__ void mlp2_fused(const ushort* __restrict__ X,
                           const ushort* __restrict__ Wt1, const ushort* __restrict__ Wt2,
                           const float* __restrict__ b1, const float* __restrict__ b2,
                           ushort* __restrict__ Yb,
                           const float* __restrict__ attp, float* __restrict__ dotout,
                           int M)
{
    __shared__ char smem[65536];
    char* Xs = smem;
    char* Ws = smem + 32768;
    const int tid  = threadIdx.x;
    const int lane = tid & 63;
    const int wid  = tid >> 6;
    const int wr = wid >> 1, wc = wid & 1;
    const int r0t = blockIdx.x * 128;
    const bool full = (r0t + 128 <= M);

    if (full) {
        stage_tile_fast<SWAP>(X, (size_t)r0t, Xs, wid, lane);
        stage_tile_fast<false>(Wt1, 0, Ws, wid, lane);
        vm_drain();                        // LDS-DMA must land before the barrier publishes
    } else {
        #pragma unroll
        for (int i = 0; i < 8; ++i) {
            int id = i * 256 + tid;
            int row = id >> 4, c = id & 15;
            int gr = r0t + row;
            short8 v = {0,0,0,0,0,0,0,0};
            if (gr < M) {
                int sr = SWAP ? (gr ^ 1) : gr;
                v = *(const short8*)(X + (size_t)sr * DIM + c * 8);
            }
            *(short8*)(Xs + lds_off(row, c)) = v;
            *(short8*)(Ws + lds_off(row, c)) = *(const short8*)(Wt1 + row * DIM + c * 8);
        }
    }
    __syncthreads();

    f32x4 acc[4][4];
    #pragma unroll
    for (int m = 0; m < 4; ++m)
        #pragma unroll
        for (int n = 0; n < 4; ++n) acc[m][n] = (f32x4){0.f, 0.f, 0.f, 0.f};

    kloop128(Xs, Ws, wr, wc, lane, acc);
    __syncthreads();                       // all LDS reads of X/W1 done

    // stage W2 (full 128-row weight tile: fast path always valid);
    // write H = relu(acc+b1) bf16 into Xs (swizzled scalar writes)
    stage_tile_fast<false>(Wt2, 0, Ws, wid, lane);
    {
        const int col0 = wc * 64 + (lane & 15);
        float b1v[4];
        #pragma unroll
        for (int n = 0; n < 4; ++n) b1v[n] = b1[col0 + n * 16];
        #pragma unroll
        for (int m = 0; m < 4; ++m)
            #pragma unroll
            for (int i = 0; i < 4; ++i) {
                int row = wr * 64 + m * 16 + (lane >> 4) * 4 + i;
                #pragma unroll
                for (int n = 0; n < 4; ++n) {
                    float v = fmaxf(acc[m][n][i] + b1v[n], 0.f);
                    int cb = (col0 + n * 16) * 2;
                    *(ushort*)(Xs + row * 256 + (((cb >> 4) ^ (row & 7)) << 4) + (cb & 15)) = f2b(v);
                }
            }
    }
    vm_drain();                            // W2 DMA landed before publish
    __syncthreads();

    #pragma unroll
    for (int m = 0; m < 4; ++m)
        #pragma unroll
        for (int n = 0; n < 4; ++n) acc[m][n] = (f32x4){0.f, 0.f, 0.f, 0.f};

    kloop128(Xs, Ws, wr, wc, lane, acc);

    const int col0 = wc * 64 + (lane & 15);
    float b2v[4], attv[4];
    #pragma unroll
    for (int n = 0; n < 4; ++n) b2v[n] = b2[col0 + n * 16];
    if (DOT)
        #pragma unroll
        for (int n = 0; n < 4; ++n) attv[n] = attp[col0 + n * 16];

    float ps[4][4];
    #pragma unroll
    for (int m = 0; m < 4; ++m)
        #pragma unroll
        for (int i = 0; i < 4; ++i) {
            int gr = r0t + wr * 64 + m * 16 + (lane >> 4) * 4 + i;
            float p = 0.f;
            #pragma unroll
            for (int n = 0; n < 4; ++n) {
                float y = acc[m][n][i] + b2v[n];
                if (gr < M) Yb[(size_t)gr * DIM + col0 + n * 16] = f2b(y);
                if (DOT) p = fmaf(y, attv[n], p);
            }
            ps[m][i] = p;
        }

    if (DOT) {
        #pragma unroll
        for (int mask = 1; mask <= 8; mask <<= 1)
            #pragma unroll
            for (int m = 0; m < 4; ++m)
                #pragma unroll
                for (int i = 0; i < 4; ++i)
                    ps[m][i] += __shfl_xor(ps[m][i], mask);
        __syncthreads();                   // smem free for reuse
        float* part = (float*)smem;        // [2][128]
        if ((lane & 15) == 0)
            #pragma unroll
            for (int m = 0; m < 4; ++m)
                #pragma unroll
                for (int i = 0; i < 4; ++i)
                    part[wc * 128 + wr * 64 + m * 16 + (lane >> 4) * 4 + i] = ps[m][i];
        __syncthreads();
        if (tid < 128) {
            int gr = r0t + tid;
            if (gr < M) dotout[gr] = part[tid] + part[128 + tid];
        }
    }
}

// ---------------------------------------------------------------------------
// Update GEMM: Y = concat_K(X1..XNIN) @ W + bias; fp32 + bf16 out; per-row att dot.
// ---------------------------------------------------------------------------
template<int NIN>
__launch_bounds__(256)
__global__ void upd_gemm(const ushort* __restrict__ X1, const ushort* __restrict__ X2,
                         const ushort* __restrict__ X3,
                         const ushort* __restrict__ Wt, const float* __restrict__ bias,
                         float* __restrict__ Yf, ushort* __restrict__ Yb,
                         const float* __restrict__ attp, float* __restrict__ dotout,
                         int M)
{
    __shared__ char smem[65536];
    char* Xs = smem;
    char* Ws = smem + 32768;
    const int tid  = threadIdx.x;
    const int lane = tid & 63;
    const int wid  = tid >> 6;
    const int wr = wid >> 1, wc = wid & 1;
    const int r0t = blockIdx.x * 128;
    const bool full = (r0t + 128 <= M);

    f32x4 acc[4][4];
    #pragma unroll
    for (int m = 0; m < 4; ++m)
        #pragma unroll
        for (int n = 0; n < 4; ++n) acc[m][n] = (f32x4){0.f, 0.f, 0.f, 0.f};

    #pragma unroll
    for (int in = 0; in < NIN; ++in) {
        const ushort* X = (in == 0) ? X1 : ((in == 1) ? X2 : X3);
        __syncthreads();                   // previous kloop's LDS reads done
        if (full) {
            stage_tile_fast<false>(X, (size_t)r0t, Xs, wid, lane);
            stage_tile_fast<false>(Wt + (size_t)in * CH, 0, Ws, wid, lane);
            vm_drain();                    // DMA landed before publish
        } else {
            #pragma unroll
            for (int i = 0; i < 8; ++i) {
                int id = i * 256 + tid;
                int row = id >> 4, c = id & 15;
                int gr = r0t + row;
                short8 v = {0,0,0,0,0,0,0,0};
                if (gr < M) v = *(const short8*)(X + (size_t)gr * DIM + c * 8);
                *(short8*)(Xs + lds_off(row, c)) = v;
                *(short8*)(Ws + lds_off(row, c)) =
                    *(const short8*)(Wt + (size_t)in * CH + row * DIM + c * 8);
            }
        }
        __syncthreads();
        kloop128(Xs, Ws, wr, wc, lane, acc);
    }

    const int col0 = wc * 64 + (lane & 15);
    float bv[4], attv[4];
    #pragma unroll
    for (int n = 0; n < 4; ++n) bv[n] = bias[col0 + n * 16];
    #pragma unroll
    for (int n = 0; n < 4; ++n) attv[n] = attp[col0 + n * 16];

    float ps[4][4];
    #pragma unroll
    for (int m = 0; m < 4; ++m)
        #pragma unroll
        for (int i = 0; i < 4; ++i) {
            int gr = r0t + wr * 64 + m * 16 + (lane >> 4) * 4 + i;
            float p = 0.f;
            #pragma unroll
            for (int n = 0; n < 4; ++n) {
                float v = acc[m][n][i] + bv[n];
                if (gr < M) {
                    Yf[(size_t)gr * DIM + col0 + n * 16] = v;
                    Yb[(size_t)gr * DIM + col0 + n * 16] = f2b(v);
                }
                p = fmaf(v, attv[n], p);
            }
            ps[m][i] = p;
        }

    #pragma unroll
    for (int mask = 1; mask <= 8; mask <<= 1)
        #pragma unroll
        for (int m = 0; m < 4; ++m)
            #pragma unroll
            for (int i = 0; i < 4; ++i)
                ps[m][i] += __shfl_xor(ps[m][i], mask);
    __syncthreads();
    float* part = (float*)smem;
    if ((lane & 15) == 0)
        #pragma unroll
        for (int m = 0; m < 4; ++m)
            #pragma unroll
            for (int i = 0; i < 4; ++i)
                part[wc * 128 + wr * 64 + m * 16 + (lane >> 4) * 4 + i] = ps[m][i];
    __syncthreads();
    if (tid < 128) {
        int gr = r0t + tid;
        if (gr < M) dotout[gr] = part[tid] + part[128 + tid];
    }
}

// ---------------------------------------------------------------------------
// one-time converts
// ---------------------------------------------------------------------------
__launch_bounds__(256)
__global__ void wtrans(const float* __restrict__ W, ushort* __restrict__ Wt)
{
    int ch  = blockIdx.y;
    int idx = blockIdx.x * 256 + threadIdx.x;
    int k = idx >> 7, c = idx & 127;
    float v = W[((size_t)ch * 128 + k) * 128 + c];
    Wt[(size_t)ch * CH + c * 128 + k] = f2b(v);
}

__launch_bounds__(256)
__global__ void cvt_copy(const float* __restrict__ in, ushort* __restrict__ out_bf,
                         float* __restrict__ out_f32, int n8)
{
    int i = blockIdx.x * 256 + threadIdx.x;
    if (i >= n8) return;
    const float4* p = (const float4*)in + (size_t)i * 2;
    float4 a = p[0], b = p[1];
    ((float4*)out_f32)[(size_t)i * 2]     = a;
    ((float4*)out_f32)[(size_t)i * 2 + 1] = b;
    ushort r[8] = {f2b(a.x), f2b(a.y), f2b(a.z), f2b(a.w),
                   f2b(b.x), f2b(b.y), f2b(b.z), f2b(b.w)};
    *(short8*)(out_bf + (size_t)i * 8) = *(short8*)r;
}

// wave-per-node dot: out[w] = dot(bf row, att[0:128])
__launch_bounds__(256)
__global__ void gemv_node(const ushort* __restrict__ bf, const float* __restrict__ att,
                          float* __restrict__ out, int M)
{
    int w = (int)((blockIdx.x * (size_t)blockDim.x + threadIdx.x) >> 6);
    if (w >= M) return;
    int lane = threadIdx.x & 63;
    int d = lane * 2;
    unsigned v = *(const unsigned*)(bf + (size_t)w * DIM + d);
    float2 a = *(const float2*)(att + d);
    float s = b2f(v & 0xffffu) * a.x + b2f(v >> 16) * a.y;
    #pragma unroll
    for (int m = 32; m >= 1; m >>= 1) s += __shfl_xor(s, m);
    if (lane == 0) out[w] = s;
}

// ---------------------------------------------------------------------------
// CSR build
// ---------------------------------------------------------------------------
__launch_bounds__(256)
__global__ void hist_kernel(const int* __restrict__ le, const int* __restrict__ ce,
                            unsigned* __restrict__ cnt_c, unsigned* __restrict__ cnt_l)
{
    int e = blockIdx.x * blockDim.x + threadIdx.x;
    if (e >= ESZ) return;
    atomicAdd(cnt_c + ce[e], 1u);
    atomicAdd(cnt_l + le[e], 1u);
}

__launch_bounds__(256)
__global__ void scan_partial(const unsigned* __restrict__ in, unsigned* __restrict__ out,
                             unsigned* __restrict__ bsum, int n)
{
    __shared__ unsigned s[256];
    int tid  = threadIdx.x;
    int base = blockIdx.x * 1024 + tid * 4;
    unsigned v[4];
    #pragma unroll
    for (int k = 0; k < 4; ++k) v[k] = (base + k < n) ? in[base + k] : 0u;
    unsigned tsum = v[0] + v[1] + v[2] + v[3];
    s[tid] = tsum;
    __syncthreads();
    for (int off = 1; off < 256; off <<= 1) {
        unsigned t = (tid >= off) ? s[tid - off] : 0u;
        __syncthreads();
        s[tid] += t;
        __syncthreads();
    }
    unsigned run = s[tid] - tsum;
    #pragma unroll
    for (int k = 0; k < 4; ++k) {
        if (base + k < n) out[base + k] = run;
        run += v[k];
    }
    if (tid == 255) bsum[blockIdx.x] = s[255];
}

__launch_bounds__(256)
__global__ void scan_top(unsigned* __restrict__ bsum, int nb)
{
    __shared__ unsigned s[256];
    int tid = threadIdx.x;
    unsigned v = (tid < nb) ? bsum[tid] : 0u;
    s[tid] = v;
    __syncthreads();
    for (int off = 1; off < 256; off <<= 1) {
        unsigned t = (tid >= off) ? s[tid - off] : 0u;
        __syncthreads();
        s[tid] += t;
        __syncthreads();
    }
    if (tid < nb) bsum[tid] = s[tid] - v;
}

__launch_bounds__(256)
__global__ void scan_add(unsigned* __restrict__ out, const unsigned* __restrict__ bsum,
                         int n, unsigned total)
{
    int i = blockIdx.x * blockDim.x + threadIdx.x;
    if (i < n) out[i] += bsum[i >> 10];
    if (i == 0) out[n] = total;
}

__launch_bounds__(256)
__global__ void scatter_kernel(const int* __restrict__ le, const int* __restrict__ ce,
                               unsigned* __restrict__ cur_c, unsigned* __restrict__ cur_l,
                               unsigned* __restrict__ perm_c, unsigned* __restrict__ perm_l,
                               unsigned* __restrict__ le_csr, unsigned* __restrict__ ce_csr)
{
    int e = blockIdx.x * blockDim.x + threadIdx.x;
    if (e >= ESZ) return;
    int lv = le[e], cv = ce[e];
    unsigned p1 = atomicAdd(cur_c + cv, 1u);
    perm_c[p1] = (unsigned)e;
    le_csr[p1] = (unsigned)lv;
    unsigned p2 = atomicAdd(cur_l + lv, 1u);
    perm_l[p2] = (unsigned)e;
    ce_csr[p2] = (unsigned)cv;
}

// ---------------------------------------------------------------------------
// clause-centric fused score + leaky-relu + segment softmax
// ---------------------------------------------------------------------------
__launch_bounds__(256)
__global__ void fused_softmax(const unsigned* __restrict__ base_c, const unsigned* __restrict__ le_csr,
                              const unsigned* __restrict__ perm_c,
                              const float* __restrict__ pc1, const float* __restrict__ ql1,
                              const float* __restrict__ pl2, const float* __restrict__ qc2,
                              float* __restrict__ W1csr, float* __restrict__ W2e,
                              float* __restrict__ D1, float* __restrict__ D2)
{
    int c = blockIdx.x * blockDim.x + threadIdx.x;
    if (c >= CSZ) return;
    unsigned b0 = base_c[c], b1 = base_c[c + 1];
    float pc = pc1[c], qc = qc2[c];
    float m1 = -1e30f, m2 = -1e30f;
    for (unsigned j = b0; j < b1; ++j) {
        unsigned lv = le_csr[j];
        float s1 = pc + ql1[lv];  s1 = (s1 > 0.f) ? s1 : 0.2f * s1;
        float s2 = pl2[lv] + qc;  s2 = (s2 > 0.f) ? s2 : 0.2f * s2;
        m1 = fmaxf(m1, s1);
        m2 = fmaxf(m2, s2);
    }
    float d1 = 0.f, d2 = 0.f;
    for (unsigned j = b0; j < b1; ++j) {
        unsigned lv = le_csr[j];
        float s1 = pc + ql1[lv];  s1 = (s1 > 0.f) ? s1 : 0.2f * s1;
        float s2 = pl2[lv] + qc;  s2 = (s2 > 0.f) ? s2 : 0.2f * s2;
        float ex1 = __expf(s1 - m1);
        float ex2 = __expf(s2 - m2);
        d1 += ex1; d2 += ex2;
        W1csr[j] = ex1;
        W2e[perm_c[j]] = ex2;
    }
    D1[c] = d1; D2[c] = d2;
}

// wave per clause: AGC[c] = (1/D1) * sum_j W1csr[j] * A[le_csr[j]]
__launch_bounds__(256)
__global__ void aggr_c(const unsigned* __restrict__ base_c, const unsigned* __restrict__ le_csr,
                       const float* __restrict__ W1csr, const float* __restrict__ D1,
                       const ushort* __restrict__ A_bf, ushort* __restrict__ AGC)
{
    int w = (int)((blockIdx.x * (size_t)blockDim.x + threadIdx.x) >> 6);
    if (w >= CSZ) return;
    int lane = threadIdx.x & 63;
    int d = lane * 2;
    unsigned b0 = base_c[w], b1 = base_c[w + 1];
    float invd = 1.f / (D1[w] + 1e-16f);
    float ax = 0.f, ay = 0.f;
    for (unsigned j = b0; j < b1; ++j) {
        float wt = W1csr[j] * invd;
        unsigned lv = le_csr[j];
        unsigned av = *(const unsigned*)(A_bf + (size_t)lv * DIM + d);
        ax = fmaf(wt, b2f(av & 0xffffu), ax);
        ay = fmaf(wt, b2f(av >> 16), ay);
    }
    *(unsigned*)(AGC + (size_t)w * DIM + d) = (unsigned)f2b(ax) | ((unsigned)f2b(ay) << 16);
}

// wave per literal: AGL[l] = sum_j (W2e[perm_l[j]]/D2[ce_csr[j]]) * B[ce_csr[j]]
__launch_bounds__(256)
__global__ void aggr_l(const unsigned* __restrict__ base_l, const unsigned* __restrict__ ce_csr,
                       const unsigned* __restrict__ perm_l,
                       const float* __restrict__ W2e, const float* __restrict__ D2,
                       const ushort* __restrict__ B_bf, ushort* __restrict__ AGL)
{
    int w = (int)((blockIdx.x * (size_t)blockDim.x + threadIdx.x) >> 6);
    if (w >= LSZ) return;
    int lane = threadIdx.x & 63;
    int d = lane * 2;
    unsigned b0 = base_l[w], b1 = base_l[w + 1];
    float ax = 0.f, ay = 0.f;
    for (unsigned j = b0; j < b1; ++j) {
        unsigned e = perm_l[j];
        unsigned cv = ce_csr[j];
        float wt = W2e[e] / (D2[cv] + 1e-16f);
        unsigned bv = *(const unsigned*)(B_bf + (size_t)cv * DIM + d);
        ax = fmaf(wt, b2f(bv & 0xffffu), ax);
        ay = fmaf(wt, b2f(bv >> 16), ay);
    }
    *(unsigned*)(AGL + (size_t)w * DIM + d) = (unsigned)f2b(ax) | ((unsigned)f2b(ay) << 16);
}

extern "C" void kernel_launch(void* const* d_in, const int* in_sizes, int n_in,
                              void* d_out, int out_size, void* d_ws, size_t ws_size,
                              hipStream_t stream)
{
    const int*   le      = (const int*)  d_in[2];
    const int*   ce      = (const int*)  d_in[3];
    const float* l_emb0  = (const float*)d_in[4];
    const float* c_emb0  = (const float*)d_in[5];
    const float* l2c_w1  = (const float*)d_in[6];
    const float* l2c_b1  = (const float*)d_in[7];
    const float* l2c_w2  = (const float*)d_in[8];
    const float* l2c_b2  = (const float*)d_in[9];
    const float* c2l_w1  = (const float*)d_in[10];
    const float* c2l_b1  = (const float*)d_in[11];
    const float* c2l_w2  = (const float*)d_in[12];
    const float* c2l_b2  = (const float*)d_in[13];
    const float* l2l_w1  = (const float*)d_in[14];
    const float* l2l_b1  = (const float*)d_in[15];
    const float* l2l_w2  = (const float*)d_in[16];
    const float* l2l_b2  = (const float*)d_in[17];
    const float* c_att   = (const float*)d_in[18];
    const float* c_upd_w = (const float*)d_in[19];
    const float* c_upd_b = (const float*)d_in[20];
    const float* l_att   = (const float*)d_in[21];
    const float* l_upd_w = (const float*)d_in[22];
    const float* l_upd_b = (const float*)d_in[23];

    float* out = (float*)d_out;
    float* outL[3] = { out,
                       out + (size_t)LSZ * DIM,
                       out + 2 * (size_t)LSZ * DIM };
    float* outC[3] = { out + 3 * (size_t)LSZ * DIM,
                       out + 3 * (size_t)LSZ * DIM + (size_t)CSZ * DIM,
                       out + 3 * (size_t)LSZ * DIM + 2 * (size_t)CSZ * DIM };

    char* p = (char*)d_ws;
    ushort* A_bf   = (ushort*)p; p += (size_t)LSZ * DIM * 2;
    ushort* B_bf   = (ushort*)p; p += (size_t)CSZ * DIM * 2;
    ushort* AGC_bf = (ushort*)p; p += (size_t)CSZ * DIM * 2;
    ushort* AGL_bf = (ushort*)p; p += (size_t)LSZ * DIM * 2;
    ushort* l_bf0  = (ushort*)p; p += (size_t)LSZ * DIM * 2;
    ushort* l_bf1  = (ushort*)p; p += (size_t)LSZ * DIM * 2;
    ushort* c_bf0  = (ushort*)p; p += (size_t)CSZ * DIM * 2;
    ushort* c_bf1  = (ushort*)p; p += (size_t)CSZ * DIM * 2;
    ushort* Wt     = (ushort*)p; p += (size_t)11 * CH * 2;
    float* W1csr = (float*)p; p += (size_t)ESZ * 4;
    float* W2e   = (float*)p; p += (size_t)ESZ * 4;
    float* pc1 = (float*)p; p += (size_t)CSZ * 4;
    float* qc2 = (float*)p; p += (size_t)CSZ * 4;
    float* ql1 = (float*)p; p += (size_t)LSZ * 4;
    float* pl2 = (float*)p; p += (size_t)LSZ * 4;
    float* D1  = (float*)p; p += (size_t)CSZ * 4;
    float* D2  = (float*)p; p += (size_t)CSZ * 4;
    unsigned* base_c = (unsigned*)p; p += (size_t)(CSZ + 1) * 4;
    unsigned* base_l = (unsigned*)p; p += (size_t)(LSZ + 1) * 4;
    unsigned* cnt_c  = (unsigned*)p; p += (size_t)CSZ * 4;
    unsigned* cnt_l  = (unsigned*)p; p += (size_t)LSZ * 4;
    unsigned* perm_c = (unsigned*)p; p += (size_t)ESZ * 4;
    unsigned* perm_l = (unsigned*)p; p += (size_t)ESZ * 4;
    unsigned* le_csr = (unsigned*)p; p += (size_t)ESZ * 4;
    unsigned* ce_csr = (unsigned*)p; p += (size_t)ESZ * 4;
    unsigned* bsum   = (unsigned*)p; p += 1024 * 4;

    const int GL128 = (LSZ + 127) / 128;
    const int GC128 = (CSZ + 127) / 128;
    const int GE_THR = (ESZ + 255) / 256;
    const int GC_THR = (CSZ + 255) / 256;
    const int GC_WAVE = (CSZ + 3) / 4;
    const int GL_WAVE = (LSZ + 3) / 4;

    // one-time converts
    cvt_copy<<<(LSZ * 16 + 255) / 256, 256, 0, stream>>>(l_emb0, l_bf0, outL[0], LSZ * 16);
    cvt_copy<<<(CSZ * 16 + 255) / 256, 256, 0, stream>>>(c_emb0, c_bf0, outC[0], CSZ * 16);
    wtrans<<<dim3(64, 1), 256, 0, stream>>>(l2c_w1, Wt + 0 * CH);
    wtrans<<<dim3(64, 1), 256, 0, stream>>>(l2c_w2, Wt + 1 * CH);
    wtrans<<<dim3(64, 1), 256, 0, stream>>>(c2l_w1, Wt + 2 * CH);
    wtrans<<<dim3(64, 1), 256, 0, stream>>>(c2l_w2, Wt + 3 * CH);
    wtrans<<<dim3(64, 1), 256, 0, stream>>>(l2l_w1, Wt + 4 * CH);
    wtrans<<<dim3(64, 1), 256, 0, stream>>>(l2l_w2, Wt + 5 * CH);
    wtrans<<<dim3(64, 2), 256, 0, stream>>>(c_upd_w, Wt + 6 * CH);
    wtrans<<<dim3(64, 3), 256, 0, stream>>>(l_upd_w, Wt + 8 * CH);

    // iter-0 attention dots on raw embeddings
    gemv_node<<<GC_WAVE, 256, 0, stream>>>(c_bf0, c_att, pc1, CSZ);
    gemv_node<<<GL_WAVE, 256, 0, stream>>>(l_bf0, l_att, pl2, LSZ);

    // CSR build (graph constant across iterations)
    hipMemsetAsync(cnt_c, 0, CSZ * sizeof(unsigned), stream);
    hipMemsetAsync(cnt_l, 0, LSZ * sizeof(unsigned), stream);
    hist_kernel<<<GE_THR, 256, 0, stream>>>(le, ce, cnt_c, cnt_l);
    int nb_c = (CSZ + 1023) / 1024;
    int nb_l = (LSZ + 1023) / 1024;
    scan_partial<<<nb_c, 256, 0, stream>>>(cnt_c, base_c, bsum, CSZ);
    scan_top<<<1, 256, 0, stream>>>(bsum, nb_c);
    scan_add<<<(CSZ + 255) / 256, 256, 0, stream>>>(base_c, bsum, CSZ, ESZ);
    scan_partial<<<nb_l, 256, 0, stream>>>(cnt_l, base_l, bsum, LSZ);
    scan_top<<<1, 256, 0, stream>>>(bsum, nb_l);
    scan_add<<<(LSZ + 255) / 256, 256, 0, stream>>>(base_l, bsum, LSZ, ESZ);
    hipMemcpyAsync(cnt_c, base_c, CSZ * sizeof(unsigned), hipMemcpyDeviceToDevice, stream);
    hipMemcpyAsync(cnt_l, base_l, LSZ * sizeof(unsigned), hipMemcpyDeviceToDevice, stream);
    scatter_kernel<<<GE_THR, 256, 0, stream>>>(le, ce, cnt_c, cnt_l, perm_c, perm_l, le_csr, ce_csr);

    for (int it = 0; it < 2; ++it) {
        const ushort* l_in = (it == 0) ? l_bf0 : l_bf1;
        const ushort* c_in = (it == 0) ? c_bf0 : c_bf1;

        // message MLPs with fused attention dots (ql1, qc2)
        mlp2_fused<false, true><<<GL128, 256, 0, stream>>>(l_in, Wt + 0 * CH, Wt + 1 * CH,
                                                           l2c_b1, l2c_b2, A_bf,
                                                           c_att + DIM, ql1, LSZ);
        mlp2_fused<false, true><<<GC128, 256, 0, stream>>>(c_in, Wt + 2 * CH, Wt + 3 * CH,
                                                           c2l_b1, c2l_b2, B_bf,
                                                           l_att + DIM, qc2, CSZ);

        // scores + segment softmax (clause-centric, both use ce segments)
        fused_softmax<<<GC_THR, 256, 0, stream>>>(base_c, le_csr, perm_c,
                                                  pc1, ql1, pl2, qc2, W1csr, W2e, D1, D2);

        // aggregation (CSR, no atomics)
        aggr_c<<<GC_WAVE, 256, 0, stream>>>(base_c, le_csr, W1csr, D1, A_bf, AGC_bf);
        aggr_l<<<GL_WAVE, 256, 0, stream>>>(base_l, ce_csr, perm_l, W2e, D2, B_bf, AGL_bf);

        // l2l message (pair-swapped input), overwrites A_bf (consumed by aggr_c)
        mlp2_fused<true, false><<<GL128, 256, 0, stream>>>(l_in, Wt + 4 * CH, Wt + 5 * CH,
                                                           l2l_b1, l2l_b2, A_bf,
                                                           nullptr, nullptr, LSZ);

        // updates: fp32 out + bf16 next-iter + next-iter attention dots (pc1, pl2)
        upd_gemm<2><<<GC128, 256, 0, stream>>>(c_in, AGC_bf, nullptr,
                                               Wt + 6 * CH, c_upd_b, outC[it + 1], c_bf1,
                                               c_att, pc1, CSZ);
        upd_gemm<3><<<GL128, 256, 0, stream>>>(l_in, AGL_bf, A_bf,
                                               Wt + 8 * CH, l_upd_b, outL[it + 1], l_bf1,
                                               l_att, pl2, LSZ);
    }
}